// Round 8
// baseline (491.414 us; speedup 1.0000x reference)
//
#include <hip/hip_runtime.h>
#include <hip/hip_bf16.h>
#include <stdint.h>

#define NN 50000   // nodes
#define DI 128     // input features
#define DO 64      // output features
#define NE 800000  // edges per relation
#define NR 4       // relations
#define NB 782     // ceil(NN/64) 64-row blocks
#define NBUCK (NR*NB)   // 3128 buckets total
#define PCHUNK 7168     // edges per place workgroup
#define PWG ((NE + PCHUNK - 1) / PCHUNK)   // 112 per relation
#define RSCAP 4096      // rowsort bucket capacity (mean 1023)

// ---------------------------------------------------------------------------
// Block-wide exclusive scan of a[0..N) in LDS. BLK threads, PER elems/thread.
// ---------------------------------------------------------------------------
template<int N, int PER, int BLK>
__device__ inline void block_exscan(int* a)
{
    __shared__ int wsum[BLK / 64];
    int tid = threadIdx.x;
    int base = tid * PER;
    int v[PER]; int s = 0;
    #pragma unroll
    for (int j = 0; j < PER; ++j) {
        int idx = base + j;
        int x = (idx < N) ? a[idx] : 0;
        v[j] = s; s += x;
    }
    int lane = tid & 63, wv = tid >> 6;
    int inc = s;
    #pragma unroll
    for (int off = 1; off < 64; off <<= 1) {
        int u = __shfl_up(inc, off);
        if (lane >= off) inc += u;
    }
    if (lane == 63) wsum[wv] = inc;
    __syncthreads();
    int woff = 0;
    for (int w = 0; w < wv; ++w) woff += wsum[w];
    int tb = woff + inc - s;
    #pragma unroll
    for (int j = 0; j < PER; ++j) {
        int idx = base + j;
        if (idx < N) a[idx] = tb + v[j];
    }
}

// ---------------------------------------------------------------------------
// GEMM v5 (fused path): grid (ceil(NN/128), NR). Block = 4 waves x 32 rows.
// W_r in LDS (per-lane ds_read, lane=col); x rows wave-uniform -> s_load.
// 32 rows/wave: 64 FMA-cycles per k against the per-k lgkm drain (~150cy),
// 5 waves/SIMD (acc[32] ~46 VGPR) -> VALU-saturated.
// ---------------------------------------------------------------------------
__global__ __launch_bounds__(256) void gemm5_kernel(
    const float* __restrict__ x, const float* __restrict__ W,
    __hip_bfloat16* __restrict__ xwb)
{
    __shared__ float Wl[DI * DO];
    int r = blockIdx.y;
    const float* Wr = W + (size_t)r * DI * DO;
    for (int i = threadIdx.x; i < DI * DO / 4; i += 256)
        ((float4*)Wl)[i] = ((const float4*)Wr)[i];
    __syncthreads();

    int wv   = __builtin_amdgcn_readfirstlane((int)(threadIdx.x >> 6));
    int lane = threadIdx.x & 63;
    int n0   = blockIdx.x * 128 + wv * 32;
    if (n0 >= NN) return;
    int nr = NN - n0; if (nr > 32) nr = 32;

    if (nr == 32) {
        const float* xr = x + (size_t)n0 * DI;   // wave-uniform base
        float acc[32];
        #pragma unroll
        for (int rr = 0; rr < 32; ++rr) acc[rr] = 0.f;
        for (int k = 0; k < DI; ++k) {
            float w = Wl[k * DO + lane];          // 1 LDS read feeds 32 FMAs
            #pragma unroll
            for (int rr = 0; rr < 32; ++rr)
                acc[rr] = fmaf(xr[(size_t)rr * DI + k], w, acc[rr]);
        }
        #pragma unroll
        for (int rr = 0; rr < 32; ++rr)
            xwb[((size_t)r * NN + n0 + rr) * DO + lane] = __float2bfloat16(acc[rr]);
    } else {
        for (int rr = 0; rr < nr; ++rr) {
            const float* xr = x + (size_t)(n0 + rr) * DI;
            float acc = 0.f;
            for (int k = 0; k < DI; ++k)
                acc = fmaf(xr[k], Wl[k * DO + lane], acc);
            xwb[((size_t)r * NN + n0 + rr) * DO + lane] = __float2bfloat16(acc);
        }
    }
}

// ---------------------------------------------------------------------------
// GEMM v1 (fallback path only): per-relation, W in LDS, x via s_load.
// ---------------------------------------------------------------------------
__global__ __launch_bounds__(256) void gemm_kernel(
    const float* __restrict__ x, const float* __restrict__ W,
    __hip_bfloat16* __restrict__ xwb)
{
    __shared__ float Wl[DI * DO];
    for (int i = threadIdx.x; i < DI * DO; i += 256) Wl[i] = W[i];
    __syncthreads();

    int wv   = __builtin_amdgcn_readfirstlane((int)(threadIdx.x >> 6));
    int lane = threadIdx.x & 63;
    int n0   = blockIdx.x * 32 + wv * 8;
    if (n0 >= NN) return;
    int nrows = NN - n0; if (nrows > 8) nrows = 8;

    if (nrows == 8) {
        const float* xr = x + (size_t)n0 * DI;
        float acc[8] = {0.f,0.f,0.f,0.f,0.f,0.f,0.f,0.f};
        #pragma unroll 8
        for (int k = 0; k < DI; ++k) {
            float w = Wl[k * DO + lane];
            #pragma unroll
            for (int rr = 0; rr < 8; ++rr)
                acc[rr] = fmaf(xr[(size_t)rr * DI + k], w, acc[rr]);
        }
        #pragma unroll
        for (int rr = 0; rr < 8; ++rr)
            xwb[(size_t)(n0 + rr) * DO + lane] = __float2bfloat16(acc[rr]);
    } else {
        for (int rr = 0; rr < nrows; ++rr) {
            const float* xr = x + (size_t)(n0 + rr) * DI;
            float acc = 0.f;
            for (int k = 0; k < DI; ++k)
                acc = fmaf(xr[k], Wl[k * DO + lane], acc);
            xwb[(size_t)(n0 + rr) * DO + lane] = __float2bfloat16(acc);
        }
    }
}

// ---------------------------------------------------------------------------
// Bucket histogram (int4-vectorized): gtot[r*NB + row>>6] += 1.
// ---------------------------------------------------------------------------
__global__ __launch_bounds__(256) void bhist_kernel(
    const int* __restrict__ rows, int* __restrict__ gtot)
{
    __shared__ int h[NB];
    int r = blockIdx.y;
    int tid = threadIdx.x;
    for (int i = tid; i < NB; i += 256) h[i] = 0;
    __syncthreads();
    const int4* rr4 = (const int4*)(rows + (size_t)r * NE);
    for (int k = blockIdx.x * 256 + tid; k < NE / 4; k += gridDim.x * 256) {
        int4 v = rr4[k];
        atomicAdd(&h[v.x >> 6], 1);
        atomicAdd(&h[v.y >> 6], 1);
        atomicAdd(&h[v.z >> 6], 1);
        atomicAdd(&h[v.w >> 6], 1);
    }
    __syncthreads();
    int* gt = gtot + r * NB;
    for (int i = tid; i < NB; i += 256)
        if (h[i]) atomicAdd(&gt[i], h[i]);
}

// ---------------------------------------------------------------------------
// Scan bucket totals -> gstart[0..NBUCK] + gcur copy.
// ---------------------------------------------------------------------------
__global__ __launch_bounds__(512) void bases_kernel(
    const int* __restrict__ gtot, int* __restrict__ gstart,
    int* __restrict__ gcur)
{
    __shared__ int a[NBUCK + 1];
    int tid = threadIdx.x;
    for (int i = tid; i < NBUCK + 1; i += 512) a[i] = (i < NBUCK) ? gtot[i] : 0;
    __syncthreads();
    block_exscan<NBUCK + 1, 7, 512>(a);
    __syncthreads();
    for (int i = tid; i < NBUCK + 1; i += 512) {
        gstart[i] = a[i];
        if (i < NBUCK) gcur[i] = a[i];
    }
}

// ---------------------------------------------------------------------------
// Placement: counting-sort a PCHUNK chunk by 64-row bucket in LDS, reserve
// global ranges, flush coalesced. Record: col:16 | rowlow:6 | bucket:10.
// ---------------------------------------------------------------------------
__global__ __launch_bounds__(512) void place_kernel(
    const int* __restrict__ rows, const int* __restrict__ cols,
    const float* __restrict__ vals, int* __restrict__ gcur,
    int2* __restrict__ csr)
{
    __shared__ int lofs[NB + 1];
    __shared__ int gbase[NB];
    __shared__ int2 stag[PCHUNK];
    int r = blockIdx.y;
    int tid = threadIdx.x;
    int e0 = blockIdx.x * PCHUNK;
    int cnt = NE - e0; if (cnt > PCHUNK) cnt = PCHUNK;
    const int*   rr = rows + (size_t)r * NE + e0;
    const int*   cc = cols + (size_t)r * NE + e0;
    const float* vv = vals + (size_t)r * NE + e0;

    for (int i = tid; i <= NB; i += 512) lofs[i] = 0;
    __syncthreads();
    for (int k = tid; k < cnt; k += 512) atomicAdd(&lofs[rr[k] >> 6], 1);
    __syncthreads();
    block_exscan<NB + 1, 2, 512>(lofs);
    __syncthreads();
    for (int b = tid; b < NB; b += 512) {
        int c = lofs[b + 1] - lofs[b];
        if (c > 0) gbase[b] = atomicAdd(&gcur[r * NB + b], c);
    }
    __syncthreads();
    for (int k = tid; k < cnt; k += 512) {
        int row = rr[k];
        int b = row >> 6;
        int slot = atomicAdd(&lofs[b], 1);
        stag[slot] = make_int2((cc[k] & 0xFFFF) | ((row & 63) << 16) | (b << 22),
                               __float_as_int(vv[k]));
    }
    __syncthreads();
    for (int i = tid; i < cnt; i += 512) {
        int2 t = stag[i];
        unsigned b2 = ((unsigned)t.x) >> 22;
        int start = b2 ? lofs[b2 - 1] : 0;
        csr[gbase[b2] + (i - start)] = t;
    }
}

// ---------------------------------------------------------------------------
// Within-bucket counting sort by row (in place) + emit per-row rowptr.
// Final write-back REWRITES the record: .x = ((r*NN + col) << 4), the
// precomputed uint2-offset of the xw row (spmm consumes it directly).
// ---------------------------------------------------------------------------
__global__ __launch_bounds__(256) void rowsort_kernel(
    int2* __restrict__ csr, const int* __restrict__ gstart,
    int* __restrict__ rowptr)
{
    __shared__ int2 stag[RSCAP];
    __shared__ int cnt[64];
    __shared__ int ofs[64];
    int blk = blockIdx.x;
    int r   = blockIdx.y;
    int b   = r * NB + blk;
    int s = gstart[b], e = gstart[b + 1];
    int cntE = e - s; if (cntE > RSCAP) cntE = RSCAP;
    int tid = threadIdx.x;
    if (tid < 64) cnt[tid] = 0;
    __syncthreads();

    int2 ed[RSCAP / 256];
    #pragma unroll
    for (int j = 0; j < RSCAP / 256; ++j) {
        int i = tid + j * 256;
        if (i < cntE) {
            ed[j] = csr[s + i];
            atomicAdd(&cnt[(ed[j].x >> 16) & 63], 1);
        }
    }
    __syncthreads();
    if (tid < 64) {
        int c = cnt[tid];
        int inc = c;
        #pragma unroll
        for (int off = 1; off < 64; off <<= 1) {
            int u = __shfl_up(inc, off);
            if (tid >= off) inc += u;
        }
        ofs[tid] = inc - c;
        int n = blk * 64 + tid;
        if (n < NN) rowptr[(size_t)r * NN + n] = s + inc - c;
        if (b == NBUCK - 1 && tid == 0)
            rowptr[(size_t)NR * NN] = gstart[NBUCK];
    }
    __syncthreads();
    #pragma unroll
    for (int j = 0; j < RSCAP / 256; ++j) {
        int i = tid + j * 256;
        if (i < cntE) {
            int rl = (ed[j].x >> 16) & 63;
            int slot = atomicAdd(&ofs[rl], 1);
            stag[slot] = ed[j];
        }
    }
    __syncthreads();
    for (int i = tid; i < cntE; i += 256) {
        int2 t = stag[i];
        t.x = (r * NN + (t.x & 0xFFFF)) << 4;   // uint2-offset of xw row
        csr[s + i] = t;
    }
}

// ---------------------------------------------------------------------------
// Fused SpMM v4: quarter-wave per edge + 2-stage pipeline.
// lane = (e4 = lane>>4: which of 4 edges, fq = lane&15: feature quad).
// Per 4 edges per relation: 2 bpermute + 1 uint2 gather + 4 FMAs/lane.
// 2 stages x 4 relations = 8 loads (32 edges) in flight.
// ---------------------------------------------------------------------------
struct Stage {
    float v[NR];
    uint2 u[NR];
};

__device__ __forceinline__ void stage_issue(
    int k, const int* deg, const int* ofsv, const float* valv,
    const uint2* __restrict__ xw2, int e4, int fq, Stage& st)
{
    #pragma unroll
    for (int r = 0; r < NR; ++r) {
        if (k < deg[r]) {                      // wave-uniform branch
            int e = k + e4;
            bool valid = e < deg[r];
            int ec = valid ? e : 0;
            int ofs  = __shfl(ofsv[r], ec);
            float vv = __shfl(valv[r], ec);
            st.v[r] = valid ? vv : 0.f;
            st.u[r] = xw2[ofs + fq];
        } else {
            st.v[r] = 0.f;
            st.u[r] = make_uint2(0u, 0u);      // avoid 0*garbage NaN
        }
    }
}

__device__ __forceinline__ void stage_consume(const Stage& st, float a[NR][4])
{
    #pragma unroll
    for (int r = 0; r < NR; ++r) {
        float v = st.v[r];
        a[r][0] = fmaf(v, __uint_as_float(st.u[r].x << 16),          a[r][0]);
        a[r][1] = fmaf(v, __uint_as_float(st.u[r].x & 0xFFFF0000u),  a[r][1]);
        a[r][2] = fmaf(v, __uint_as_float(st.u[r].y << 16),          a[r][2]);
        a[r][3] = fmaf(v, __uint_as_float(st.u[r].y & 0xFFFF0000u),  a[r][3]);
    }
}

__global__ __launch_bounds__(256) void spmm_fused_kernel(
    const uint2* __restrict__ xw2, const int2* __restrict__ csr,
    const int* __restrict__ rowptr, const float* __restrict__ bias,
    float* __restrict__ out)
{
    int n = __builtin_amdgcn_readfirstlane(
        (int)((blockIdx.x * 256 + threadIdx.x) >> 6));
    int lane = threadIdx.x & 63;
    int e4 = lane >> 4, fq = lane & 15;
    if (n >= NN) return;

    int deg[NR]; int ofsv[NR]; float valv[NR];
    int sbeg[NR], send[NR];
    int maxdeg = 0;
    #pragma unroll
    for (int r = 0; r < NR; ++r) {
        sbeg[r] = rowptr[(size_t)r * NN + n];
        send[r] = rowptr[(size_t)r * NN + n + 1];
        int d = send[r] - sbeg[r];
        if (d > 64) d = 64;
        deg[r] = d;
        int2 cv = (lane < d) ? csr[sbeg[r] + lane] : make_int2(0, 0);
        ofsv[r] = cv.x;                        // precomputed uint2 offset
        valv[r] = __int_as_float(cv.y);
        maxdeg = max(maxdeg, d);
    }

    float a[NR][4];
    #pragma unroll
    for (int r = 0; r < NR; ++r)
        #pragma unroll
        for (int j = 0; j < 4; ++j) a[r][j] = 0.f;

    Stage A, B;
    stage_issue(0, deg, ofsv, valv, xw2, e4, fq, A);
    for (int k = 0; k < maxdeg; k += 8) {
        stage_issue(k + 4, deg, ofsv, valv, xw2, e4, fq, B);
        stage_consume(A, a);
        stage_issue(k + 8, deg, ofsv, valv, xw2, e4, fq, A);
        stage_consume(B, a);
    }

    // rare tail: deg > 64 (group 0 accumulates; others add 0)
    #pragma unroll
    for (int r = 0; r < NR; ++r) {
        for (int i = sbeg[r] + 64; i < send[r]; ++i) {   // ~never taken
            int2 cv = csr[i];
            float v = (lane < 16) ? __int_as_float(cv.y) : 0.f;
            uint2 u = xw2[cv.x + fq];
            a[r][0] = fmaf(v, __uint_as_float(u.x << 16),         a[r][0]);
            a[r][1] = fmaf(v, __uint_as_float(u.x & 0xFFFF0000u), a[r][1]);
            a[r][2] = fmaf(v, __uint_as_float(u.y << 16),         a[r][2]);
            a[r][3] = fmaf(v, __uint_as_float(u.y & 0xFFFF0000u), a[r][3]);
        }
    }

    // reduce over the 4 edge-groups; then bias+relu+sum across relations
    float t[4] = {0.f, 0.f, 0.f, 0.f};
    #pragma unroll
    for (int r = 0; r < NR; ++r) {
        #pragma unroll
        for (int j = 0; j < 4; ++j) {
            a[r][j] += __shfl_xor(a[r][j], 16);
            a[r][j] += __shfl_xor(a[r][j], 32);
        }
        float4 br = *(const float4*)&bias[r * DO + 4 * fq];
        t[0] += fmaxf(a[r][0] + br.x, 0.f);
        t[1] += fmaxf(a[r][1] + br.y, 0.f);
        t[2] += fmaxf(a[r][2] + br.z, 0.f);
        t[3] += fmaxf(a[r][3] + br.w, 0.f);
    }
    float s2 = t[0]*t[0] + t[1]*t[1] + t[2]*t[2] + t[3]*t[3];
    #pragma unroll
    for (int off = 8; off >= 1; off >>= 1) s2 += __shfl_xor(s2, off);
    float inv = 1.0f / fmaxf(sqrtf(s2), 1e-12f);
    if (lane < 16) {
        float4 o = make_float4(t[0]*inv, t[1]*inv, t[2]*inv, t[3]*inv);
        *(float4*)&out[(size_t)n * DO + 4 * fq] = o;
    }
}

// ---------------------------------------------------------------------------
// Fallback path (small ws): R1 atomic-scatter pipeline.
// ---------------------------------------------------------------------------
__global__ __launch_bounds__(256) void scatter_kernel(
    const __hip_bfloat16* __restrict__ xwb, const float* __restrict__ vals,
    const int* __restrict__ rows, const int* __restrict__ cols,
    float* __restrict__ agg)
{
    const int nPairs = NE / 2;
    int gwave  = (blockIdx.x * 256 + threadIdx.x) >> 6;
    int half   = (threadIdx.x >> 5) & 1;
    int l32    = threadIdx.x & 31;
    int stride = gridDim.x * 4;
    const uint16_t* xw16 = reinterpret_cast<const uint16_t*>(xwb);
    for (int p = gwave; p < nPairs; p += stride) {
        int e = 2 * p + half;
        int row = rows[e]; int col = cols[e]; float v = vals[e];
        uint32_t packed = *reinterpret_cast<const uint32_t*>(
            xw16 + ((size_t)col << 6) + 2 * l32);
        float f0 = __uint_as_float(packed << 16);
        float f1 = __uint_as_float(packed & 0xFFFF0000u);
        float* dst = agg + ((size_t)row << 6) + 2 * l32;
        atomicAdd(dst,     v * f0);
        atomicAdd(dst + 1, v * f1);
    }
}

__global__ __launch_bounds__(256) void accum_kernel(
    float* __restrict__ agg, const float* __restrict__ b,
    float* __restrict__ out, int first)
{
    int i = blockIdx.x * 256 + threadIdx.x;
    if (i >= NN * DO) return;
    float v = agg[i] + b[i & (DO - 1)];
    agg[i] = 0.f;
    v = fmaxf(v, 0.f);
    out[i] = first ? v : (out[i] + v);
}

__global__ __launch_bounds__(256) void norm_kernel(float* __restrict__ out)
{
    int n = (blockIdx.x * 256 + threadIdx.x) >> 6;
    int lane = threadIdx.x & 63;
    if (n >= NN) return;
    size_t idx = (size_t)n * DO + lane;
    float t = out[idx];
    float s = t * t;
    #pragma unroll
    for (int off = 32; off >= 1; off >>= 1) s += __shfl_xor(s, off);
    out[idx] = t / fmaxf(sqrtf(s), 1e-12f);
}

extern "C" void kernel_launch(void* const* d_in, const int* in_sizes, int n_in,
                              void* d_out, int out_size, void* d_ws, size_t ws_size,
                              hipStream_t stream)
{
    const float* x    = (const float*)d_in[0];
    const float* W    = (const float*)d_in[1];
    const float* b    = (const float*)d_in[2];
    const float* vals = (const float*)d_in[3];
    const int*   rows = (const int*)d_in[4];
    const int*   cols = (const int*)d_in[5];
    float* out = (float*)d_out;
    char* ws = (char*)d_ws;

    // ws: xwb 25.6MB | csr 25.6MB | rowptr 3.2MB | gtot | gstart | gcur
    const size_t O_XW = 0;
    const size_t O_CS = O_XW + (size_t)NR * NN * DO * 2;
    const size_t O_RP = O_CS + (size_t)NR * NE * 8;
    const size_t O_GT = O_RP + ((size_t)NR * NN + 4) * 4;
    const size_t O_GS = O_GT + (size_t)NBUCK * 4;
    const size_t O_GC = O_GS + (size_t)(NBUCK + 1) * 4;
    const size_t NEED = O_GC + (size_t)NBUCK * 4;

    if (ws_size >= NEED) {
        __hip_bfloat16* xwb = (__hip_bfloat16*)(ws + O_XW);
        int2* csr   = (int2*)(ws + O_CS);
        int* rowptr = (int*)(ws + O_RP);
        int* gtot   = (int*)(ws + O_GT);
        int* gstart = (int*)(ws + O_GS);
        int* gcur   = (int*)(ws + O_GC);

        hipMemsetAsync(gtot, 0, (size_t)NBUCK * 4, stream);
        gemm5_kernel<<<dim3((NN + 127) / 128, NR), dim3(256), 0, stream>>>(x, W, xwb);
        bhist_kernel<<<dim3(32, NR), dim3(256), 0, stream>>>(rows, gtot);
        bases_kernel<<<dim3(1), dim3(512), 0, stream>>>(gtot, gstart, gcur);
        place_kernel<<<dim3(PWG, NR), dim3(512), 0, stream>>>(rows, cols, vals, gcur, csr);
        rowsort_kernel<<<dim3(NB, NR), dim3(256), 0, stream>>>(csr, gstart, rowptr);
        spmm_fused_kernel<<<dim3((NN * 64 + 255) / 256), dim3(256), 0, stream>>>(
            (const uint2*)xwb, csr, rowptr, b, out);
    } else {
        // sequential atomic-scatter fallback (19.2MB)
        __hip_bfloat16* xwb = (__hip_bfloat16*)ws;
        float* agg = (float*)(ws + (size_t)NN * DO * 2);
        hipMemsetAsync(agg, 0, (size_t)NN * DO * 4, stream);
        for (int r = 0; r < NR; ++r) {
            gemm_kernel<<<dim3((NN + 31) / 32), dim3(256), 0, stream>>>(
                x, W + (size_t)r * DI * DO, xwb);
            scatter_kernel<<<dim3(2048), dim3(256), 0, stream>>>(
                xwb, vals + (size_t)r * NE, rows + (size_t)r * NE,
                cols + (size_t)r * NE, agg);
            accum_kernel<<<dim3((NN * DO + 255) / 256), dim3(256), 0, stream>>>(
                agg, b + (size_t)r * DO, out, r == 0);
        }
        norm_kernel<<<dim3((NN * DO + 255) / 256), dim3(256), 0, stream>>>(out);
    }
}

// Round 9
// 188.771 us; speedup vs baseline: 2.6032x; 2.6032x over previous
//
#include <hip/hip_runtime.h>
#include <hip/hip_bf16.h>
#include <stdint.h>

#define NN 50000   // nodes
#define DI 128     // input features
#define DO 64      // output features
#define NE 800000  // edges per relation
#define NR 4       // relations
#define NB 782     // ceil(NN/64) 64-row blocks
#define NBUCK (NR*NB)   // 3128 buckets total
#define PCHUNK 7168     // edges per place workgroup
#define PWG ((NE + PCHUNK - 1) / PCHUNK)   // 112 per relation
#define RSCAP 4096      // rowsort bucket capacity (mean 1023)

typedef short short8 __attribute__((ext_vector_type(8)));
typedef float f32x4  __attribute__((ext_vector_type(4)));
union FragU { uint4 u; short8 s; };

__device__ __forceinline__ uint32_t bfb(float f)
{
    __hip_bfloat16 h = __float2bfloat16(f);
    return (uint32_t)*reinterpret_cast<unsigned short*>(&h);
}

// ---------------------------------------------------------------------------
// Block-wide exclusive scan of a[0..N) in LDS. BLK threads, PER elems/thread.
// ---------------------------------------------------------------------------
template<int N, int PER, int BLK>
__device__ inline void block_exscan(int* a)
{
    __shared__ int wsum[BLK / 64];
    int tid = threadIdx.x;
    int base = tid * PER;
    int v[PER]; int s = 0;
    #pragma unroll
    for (int j = 0; j < PER; ++j) {
        int idx = base + j;
        int x = (idx < N) ? a[idx] : 0;
        v[j] = s; s += x;
    }
    int lane = tid & 63, wv = tid >> 6;
    int inc = s;
    #pragma unroll
    for (int off = 1; off < 64; off <<= 1) {
        int u = __shfl_up(inc, off);
        if (lane >= off) inc += u;
    }
    if (lane == 63) wsum[wv] = inc;
    __syncthreads();
    int woff = 0;
    for (int w = 0; w < wv; ++w) woff += wsum[w];
    int tb = woff + inc - s;
    #pragma unroll
    for (int j = 0; j < PER; ++j) {
        int idx = base + j;
        if (idx < N) a[idx] = tb + v[j];
    }
}

// ---------------------------------------------------------------------------
// Convert x f32 -> bf16 (row-major [NN][DI]), packed stores.
// ---------------------------------------------------------------------------
__global__ __launch_bounds__(256) void convx_kernel(
    const float* __restrict__ x, uint2* __restrict__ xb)
{
    int i = blockIdx.x * 256 + threadIdx.x;
    int stride = gridDim.x * 256;
    const int total = NN * DI / 4;
    const float4* x4 = (const float4*)x;
    for (; i < total; i += stride) {
        float4 v = x4[i];
        uint2 o;
        o.x = bfb(v.x) | (bfb(v.y) << 16);
        o.y = bfb(v.z) | (bfb(v.w) << 16);
        xb[i] = o;
    }
}

// ---------------------------------------------------------------------------
// Transpose W [NR][DI][DO] f32 -> Wt [NR][DO][DI] bf16.
// ---------------------------------------------------------------------------
__global__ __launch_bounds__(256) void wtrans_kernel(
    const float* __restrict__ W, uint16_t* __restrict__ wt)
{
    int i = blockIdx.x * 256 + threadIdx.x;   // 32768 total
    if (i >= NR * DI * DO) return;
    int r = i >> 13;            // /(DI*DO)
    int k = (i >> 6) & 127;
    int n = i & 63;
    wt[((size_t)(r * DO + n) << 7) + k] = (uint16_t)bfb(W[i]);
}

// ---------------------------------------------------------------------------
// MFMA GEMM: xw[r] = x @ W_r, bf16 in/out, f32 accum.
// One wave = 16-row tile x all 4 relations x 64 cols.
// A-frag: lane holds x_bf[n0 + (l&15)][32*ks + 8*(l>>4) .. +8] (one b128).
// B-frag: lane holds Wt[r][16*ct + (l&15)][same k range] (one b128).
// A,B use the SAME contiguous-8 k-order -> any HW k-permutation cancels.
// D: col = lane&15, row = (lane>>4)*4 + reg  [measured m89].
// ---------------------------------------------------------------------------
__global__ __launch_bounds__(256) void gemm_mfma_kernel(
    const uint4* __restrict__ xb4, const uint4* __restrict__ wt4,
    uint16_t* __restrict__ xwb)
{
    int tid = threadIdx.x;
    int wv = __builtin_amdgcn_readfirstlane(tid >> 6);
    int lane = tid & 63;
    int n0 = blockIdx.x * 64 + wv * 16;
    if (n0 >= NN) return;
    int m16 = lane & 15, g = lane >> 4;

    FragU a[4];
    #pragma unroll
    for (int ks = 0; ks < 4; ++ks)
        a[ks].u = xb4[(size_t)(n0 + m16) * 16 + ks * 4 + g];

    #pragma unroll
    for (int r = 0; r < NR; ++r) {
        #pragma unroll
        for (int ct = 0; ct < 4; ++ct) {
            f32x4 acc = {0.f, 0.f, 0.f, 0.f};
            #pragma unroll
            for (int ks = 0; ks < 4; ++ks) {
                FragU b;
                b.u = wt4[(size_t)((r * DO + ct * 16 + m16) * 16) + ks * 4 + g];
                acc = __builtin_amdgcn_mfma_f32_16x16x32_bf16(
                    a[ks].s, b.s, acc, 0, 0, 0);
            }
            #pragma unroll
            for (int j = 0; j < 4; ++j) {
                int m = g * 4 + j;
                xwb[((size_t)r * NN + n0 + m) * 64 + ct * 16 + m16] =
                    (uint16_t)bfb(acc[j]);
            }
        }
    }
}

// ---------------------------------------------------------------------------
// GEMM v1 (fallback path only): per-relation, W in LDS, x via s_load.
// ---------------------------------------------------------------------------
__global__ __launch_bounds__(256) void gemm_kernel(
    const float* __restrict__ x, const float* __restrict__ W,
    __hip_bfloat16* __restrict__ xwb)
{
    __shared__ float Wl[DI * DO];
    for (int i = threadIdx.x; i < DI * DO; i += 256) Wl[i] = W[i];
    __syncthreads();

    int wv   = __builtin_amdgcn_readfirstlane((int)(threadIdx.x >> 6));
    int lane = threadIdx.x & 63;
    int n0   = blockIdx.x * 32 + wv * 8;
    if (n0 >= NN) return;
    int nrows = NN - n0; if (nrows > 8) nrows = 8;

    if (nrows == 8) {
        const float* xr = x + (size_t)n0 * DI;
        float acc[8] = {0.f,0.f,0.f,0.f,0.f,0.f,0.f,0.f};
        #pragma unroll 8
        for (int k = 0; k < DI; ++k) {
            float w = Wl[k * DO + lane];
            #pragma unroll
            for (int rr = 0; rr < 8; ++rr)
                acc[rr] = fmaf(xr[(size_t)rr * DI + k], w, acc[rr]);
        }
        #pragma unroll
        for (int rr = 0; rr < 8; ++rr)
            xwb[(size_t)(n0 + rr) * DO + lane] = __float2bfloat16(acc[rr]);
    } else {
        for (int rr = 0; rr < nrows; ++rr) {
            const float* xr = x + (size_t)(n0 + rr) * DI;
            float acc = 0.f;
            for (int k = 0; k < DI; ++k)
                acc = fmaf(xr[k], Wl[k * DO + lane], acc);
            xwb[(size_t)(n0 + rr) * DO + lane] = __float2bfloat16(acc);
        }
    }
}

// ---------------------------------------------------------------------------
// Bucket histogram (int4-vectorized): gtot[r*NB + row>>6] += 1.
// ---------------------------------------------------------------------------
__global__ __launch_bounds__(256) void bhist_kernel(
    const int* __restrict__ rows, int* __restrict__ gtot)
{
    __shared__ int h[NB];
    int r = blockIdx.y;
    int tid = threadIdx.x;
    for (int i = tid; i < NB; i += 256) h[i] = 0;
    __syncthreads();
    const int4* rr4 = (const int4*)(rows + (size_t)r * NE);
    for (int k = blockIdx.x * 256 + tid; k < NE / 4; k += gridDim.x * 256) {
        int4 v = rr4[k];
        atomicAdd(&h[v.x >> 6], 1);
        atomicAdd(&h[v.y >> 6], 1);
        atomicAdd(&h[v.z >> 6], 1);
        atomicAdd(&h[v.w >> 6], 1);
    }
    __syncthreads();
    int* gt = gtot + r * NB;
    for (int i = tid; i < NB; i += 256)
        if (h[i]) atomicAdd(&gt[i], h[i]);
}

// ---------------------------------------------------------------------------
// Scan bucket totals -> gstart[0..NBUCK] + gcur copy.
// ---------------------------------------------------------------------------
__global__ __launch_bounds__(512) void bases_kernel(
    const int* __restrict__ gtot, int* __restrict__ gstart,
    int* __restrict__ gcur)
{
    __shared__ int a[NBUCK + 1];
    int tid = threadIdx.x;
    for (int i = tid; i < NBUCK + 1; i += 512) a[i] = (i < NBUCK) ? gtot[i] : 0;
    __syncthreads();
    block_exscan<NBUCK + 1, 7, 512>(a);
    __syncthreads();
    for (int i = tid; i < NBUCK + 1; i += 512) {
        gstart[i] = a[i];
        if (i < NBUCK) gcur[i] = a[i];
    }
}

// ---------------------------------------------------------------------------
// Placement: counting-sort a PCHUNK chunk by 64-row bucket in LDS, reserve
// global ranges, flush coalesced. Record: col:16 | rowlow:6 | bucket:10.
// ---------------------------------------------------------------------------
__global__ __launch_bounds__(512) void place_kernel(
    const int* __restrict__ rows, const int* __restrict__ cols,
    const float* __restrict__ vals, int* __restrict__ gcur,
    int2* __restrict__ csr)
{
    __shared__ int lofs[NB + 1];
    __shared__ int gbase[NB];
    __shared__ int2 stag[PCHUNK];
    int r = blockIdx.y;
    int tid = threadIdx.x;
    int e0 = blockIdx.x * PCHUNK;
    int cnt = NE - e0; if (cnt > PCHUNK) cnt = PCHUNK;
    const int*   rr = rows + (size_t)r * NE + e0;
    const int*   cc = cols + (size_t)r * NE + e0;
    const float* vv = vals + (size_t)r * NE + e0;

    for (int i = tid; i <= NB; i += 512) lofs[i] = 0;
    __syncthreads();
    for (int k = tid; k < cnt; k += 512) atomicAdd(&lofs[rr[k] >> 6], 1);
    __syncthreads();
    block_exscan<NB + 1, 2, 512>(lofs);
    __syncthreads();
    for (int b = tid; b < NB; b += 512) {
        int c = lofs[b + 1] - lofs[b];
        if (c > 0) gbase[b] = atomicAdd(&gcur[r * NB + b], c);
    }
    __syncthreads();
    for (int k = tid; k < cnt; k += 512) {
        int row = rr[k];
        int b = row >> 6;
        int slot = atomicAdd(&lofs[b], 1);
        stag[slot] = make_int2((cc[k] & 0xFFFF) | ((row & 63) << 16) | (b << 22),
                               __float_as_int(vv[k]));
    }
    __syncthreads();
    for (int i = tid; i < cnt; i += 512) {
        int2 t = stag[i];
        unsigned b2 = ((unsigned)t.x) >> 22;
        int start = b2 ? lofs[b2 - 1] : 0;
        csr[gbase[b2] + (i - start)] = t;
    }
}

// ---------------------------------------------------------------------------
// Within-bucket counting sort by row (in place) + emit per-row rowptr.
// Final write-back REWRITES the record: .x = ((r*NN + col) << 4), the
// precomputed uint2-offset of the xw row (spmm consumes it directly).
// ---------------------------------------------------------------------------
__global__ __launch_bounds__(256) void rowsort_kernel(
    int2* __restrict__ csr, const int* __restrict__ gstart,
    int* __restrict__ rowptr)
{
    __shared__ int2 stag[RSCAP];
    __shared__ int cnt[64];
    __shared__ int ofs[64];
    int blk = blockIdx.x;
    int r   = blockIdx.y;
    int b   = r * NB + blk;
    int s = gstart[b], e = gstart[b + 1];
    int cntE = e - s; if (cntE > RSCAP) cntE = RSCAP;
    int tid = threadIdx.x;
    if (tid < 64) cnt[tid] = 0;
    __syncthreads();

    int2 ed[RSCAP / 256];
    #pragma unroll
    for (int j = 0; j < RSCAP / 256; ++j) {
        int i = tid + j * 256;
        if (i < cntE) {
            ed[j] = csr[s + i];
            atomicAdd(&cnt[(ed[j].x >> 16) & 63], 1);
        }
    }
    __syncthreads();
    if (tid < 64) {
        int c = cnt[tid];
        int inc = c;
        #pragma unroll
        for (int off = 1; off < 64; off <<= 1) {
            int u = __shfl_up(inc, off);
            if (tid >= off) inc += u;
        }
        ofs[tid] = inc - c;
        int n = blk * 64 + tid;
        if (n < NN) rowptr[(size_t)r * NN + n] = s + inc - c;
        if (b == NBUCK - 1 && tid == 0)
            rowptr[(size_t)NR * NN] = gstart[NBUCK];
    }
    __syncthreads();
    #pragma unroll
    for (int j = 0; j < RSCAP / 256; ++j) {
        int i = tid + j * 256;
        if (i < cntE) {
            int rl = (ed[j].x >> 16) & 63;
            int slot = atomicAdd(&ofs[rl], 1);
            stag[slot] = ed[j];
        }
    }
    __syncthreads();
    for (int i = tid; i < cntE; i += 256) {
        int2 t = stag[i];
        t.x = (r * NN + (t.x & 0xFFFF)) << 4;   // uint2-offset of xw row
        csr[s + i] = t;
    }
}

// ---------------------------------------------------------------------------
// Fused SpMM v4: quarter-wave per edge + 2-stage pipeline.
// ---------------------------------------------------------------------------
struct Stage {
    float v[NR];
    uint2 u[NR];
};

__device__ __forceinline__ void stage_issue(
    int k, const int* deg, const int* ofsv, const float* valv,
    const uint2* __restrict__ xw2, int e4, int fq, Stage& st)
{
    #pragma unroll
    for (int r = 0; r < NR; ++r) {
        if (k < deg[r]) {                      // wave-uniform branch
            int e = k + e4;
            bool valid = e < deg[r];
            int ec = valid ? e : 0;
            int ofs  = __shfl(ofsv[r], ec);
            float vv = __shfl(valv[r], ec);
            st.v[r] = valid ? vv : 0.f;
            st.u[r] = xw2[ofs + fq];
        } else {
            st.v[r] = 0.f;
            st.u[r] = make_uint2(0u, 0u);      // avoid 0*garbage NaN
        }
    }
}

__device__ __forceinline__ void stage_consume(const Stage& st, float a[NR][4])
{
    #pragma unroll
    for (int r = 0; r < NR; ++r) {
        float v = st.v[r];
        a[r][0] = fmaf(v, __uint_as_float(st.u[r].x << 16),          a[r][0]);
        a[r][1] = fmaf(v, __uint_as_float(st.u[r].x & 0xFFFF0000u),  a[r][1]);
        a[r][2] = fmaf(v, __uint_as_float(st.u[r].y << 16),          a[r][2]);
        a[r][3] = fmaf(v, __uint_as_float(st.u[r].y & 0xFFFF0000u),  a[r][3]);
    }
}

__global__ __launch_bounds__(256) void spmm_fused_kernel(
    const uint2* __restrict__ xw2, const int2* __restrict__ csr,
    const int* __restrict__ rowptr, const float* __restrict__ bias,
    float* __restrict__ out)
{
    int n = __builtin_amdgcn_readfirstlane(
        (int)((blockIdx.x * 256 + threadIdx.x) >> 6));
    int lane = threadIdx.x & 63;
    int e4 = lane >> 4, fq = lane & 15;
    if (n >= NN) return;

    int deg[NR]; int ofsv[NR]; float valv[NR];
    int sbeg[NR], send[NR];
    int maxdeg = 0;
    #pragma unroll
    for (int r = 0; r < NR; ++r) {
        sbeg[r] = rowptr[(size_t)r * NN + n];
        send[r] = rowptr[(size_t)r * NN + n + 1];
        int d = send[r] - sbeg[r];
        if (d > 64) d = 64;
        deg[r] = d;
        int2 cv = (lane < d) ? csr[sbeg[r] + lane] : make_int2(0, 0);
        ofsv[r] = cv.x;                        // precomputed uint2 offset
        valv[r] = __int_as_float(cv.y);
        maxdeg = max(maxdeg, d);
    }

    float a[NR][4];
    #pragma unroll
    for (int r = 0; r < NR; ++r)
        #pragma unroll
        for (int j = 0; j < 4; ++j) a[r][j] = 0.f;

    Stage A, B;
    stage_issue(0, deg, ofsv, valv, xw2, e4, fq, A);
    for (int k = 0; k < maxdeg; k += 8) {
        stage_issue(k + 4, deg, ofsv, valv, xw2, e4, fq, B);
        stage_consume(A, a);
        stage_issue(k + 8, deg, ofsv, valv, xw2, e4, fq, A);
        stage_consume(B, a);
    }

    // rare tail: deg > 64 (group 0 accumulates; others add 0)
    #pragma unroll
    for (int r = 0; r < NR; ++r) {
        for (int i = sbeg[r] + 64; i < send[r]; ++i) {   // ~never taken
            int2 cv = csr[i];
            float v = (lane < 16) ? __int_as_float(cv.y) : 0.f;
            uint2 u = xw2[cv.x + fq];
            a[r][0] = fmaf(v, __uint_as_float(u.x << 16),         a[r][0]);
            a[r][1] = fmaf(v, __uint_as_float(u.x & 0xFFFF0000u), a[r][1]);
            a[r][2] = fmaf(v, __uint_as_float(u.y << 16),         a[r][2]);
            a[r][3] = fmaf(v, __uint_as_float(u.y & 0xFFFF0000u), a[r][3]);
        }
    }

    // reduce over the 4 edge-groups; then bias+relu+sum across relations
    float t[4] = {0.f, 0.f, 0.f, 0.f};
    #pragma unroll
    for (int r = 0; r < NR; ++r) {
        #pragma unroll
        for (int j = 0; j < 4; ++j) {
            a[r][j] += __shfl_xor(a[r][j], 16);
            a[r][j] += __shfl_xor(a[r][j], 32);
        }
        float4 br = *(const float4*)&bias[r * DO + 4 * fq];
        t[0] += fmaxf(a[r][0] + br.x, 0.f);
        t[1] += fmaxf(a[r][1] + br.y, 0.f);
        t[2] += fmaxf(a[r][2] + br.z, 0.f);
        t[3] += fmaxf(a[r][3] + br.w, 0.f);
    }
    float s2 = t[0]*t[0] + t[1]*t[1] + t[2]*t[2] + t[3]*t[3];
    #pragma unroll
    for (int off = 8; off >= 1; off >>= 1) s2 += __shfl_xor(s2, off);
    float inv = 1.0f / fmaxf(sqrtf(s2), 1e-12f);
    if (lane < 16) {
        float4 o = make_float4(t[0]*inv, t[1]*inv, t[2]*inv, t[3]*inv);
        *(float4*)&out[(size_t)n * DO + 4 * fq] = o;
    }
}

// ---------------------------------------------------------------------------
// Fallback path (small ws): R1 atomic-scatter pipeline.
// ---------------------------------------------------------------------------
__global__ __launch_bounds__(256) void scatter_kernel(
    const __hip_bfloat16* __restrict__ xwb, const float* __restrict__ vals,
    const int* __restrict__ rows, const int* __restrict__ cols,
    float* __restrict__ agg)
{
    const int nPairs = NE / 2;
    int gwave  = (blockIdx.x * 256 + threadIdx.x) >> 6;
    int half   = (threadIdx.x >> 5) & 1;
    int l32    = threadIdx.x & 31;
    int stride = gridDim.x * 4;
    const uint16_t* xw16 = reinterpret_cast<const uint16_t*>(xwb);
    for (int p = gwave; p < nPairs; p += stride) {
        int e = 2 * p + half;
        int row = rows[e]; int col = cols[e]; float v = vals[e];
        uint32_t packed = *reinterpret_cast<const uint32_t*>(
            xw16 + ((size_t)col << 6) + 2 * l32);
        float f0 = __uint_as_float(packed << 16);
        float f1 = __uint_as_float(packed & 0xFFFF0000u);
        float* dst = agg + ((size_t)row << 6) + 2 * l32;
        atomicAdd(dst,     v * f0);
        atomicAdd(dst + 1, v * f1);
    }
}

__global__ __launch_bounds__(256) void accum_kernel(
    float* __restrict__ agg, const float* __restrict__ b,
    float* __restrict__ out, int first)
{
    int i = blockIdx.x * 256 + threadIdx.x;
    if (i >= NN * DO) return;
    float v = agg[i] + b[i & (DO - 1)];
    agg[i] = 0.f;
    v = fmaxf(v, 0.f);
    out[i] = first ? v : (out[i] + v);
}

__global__ __launch_bounds__(256) void norm_kernel(float* __restrict__ out)
{
    int n = (blockIdx.x * 256 + threadIdx.x) >> 6;
    int lane = threadIdx.x & 63;
    if (n >= NN) return;
    size_t idx = (size_t)n * DO + lane;
    float t = out[idx];
    float s = t * t;
    #pragma unroll
    for (int off = 32; off >= 1; off >>= 1) s += __shfl_xor(s, off);
    out[idx] = t / fmaxf(sqrtf(s), 1e-12f);
}

extern "C" void kernel_launch(void* const* d_in, const int* in_sizes, int n_in,
                              void* d_out, int out_size, void* d_ws, size_t ws_size,
                              hipStream_t stream)
{
    const float* x    = (const float*)d_in[0];
    const float* W    = (const float*)d_in[1];
    const float* b    = (const float*)d_in[2];
    const float* vals = (const float*)d_in[3];
    const int*   rows = (const int*)d_in[4];
    const int*   cols = (const int*)d_in[5];
    float* out = (float*)d_out;
    char* ws = (char*)d_ws;

    // ws: xwb 25.6MB | csr 25.6MB | rowptr 3.2MB | gtot | gstart | gcur
    // xb (12.8MB) + Wt (64KB) OVERLAY the csr region (dead before place).
    const size_t O_XW = 0;
    const size_t O_CS = O_XW + (size_t)NR * NN * DO * 2;
    const size_t O_RP = O_CS + (size_t)NR * NE * 8;
    const size_t O_GT = O_RP + ((size_t)NR * NN + 4) * 4;
    const size_t O_GS = O_GT + (size_t)NBUCK * 4;
    const size_t O_GC = O_GS + (size_t)(NBUCK + 1) * 4;
    const size_t NEED = O_GC + (size_t)NBUCK * 4;
    const size_t O_XB = O_CS;                         // bf16 x, 12.8MB
    const size_t O_WT = O_CS + 13u * 1024 * 1024;     // bf16 W^T, 64KB

    if (ws_size >= NEED) {
        __hip_bfloat16* xwb = (__hip_bfloat16*)(ws + O_XW);
        int2* csr   = (int2*)(ws + O_CS);
        int* rowptr = (int*)(ws + O_RP);
        int* gtot   = (int*)(ws + O_GT);
        int* gstart = (int*)(ws + O_GS);
        int* gcur   = (int*)(ws + O_GC);
        uint2* xb   = (uint2*)(ws + O_XB);
        uint16_t* wt = (uint16_t*)(ws + O_WT);

        hipMemsetAsync(gtot, 0, (size_t)NBUCK * 4, stream);
        convx_kernel<<<dim3(2048), dim3(256), 0, stream>>>(x, xb);
        wtrans_kernel<<<dim3(128), dim3(256), 0, stream>>>(W, wt);
        gemm_mfma_kernel<<<dim3(NB), dim3(256), 0, stream>>>(
            (const uint4*)xb, (const uint4*)wt, (uint16_t*)xwb);
        bhist_kernel<<<dim3(32, NR), dim3(256), 0, stream>>>(rows, gtot);
        bases_kernel<<<dim3(1), dim3(512), 0, stream>>>(gtot, gstart, gcur);
        place_kernel<<<dim3(PWG, NR), dim3(512), 0, stream>>>(rows, cols, vals, gcur, csr);
        rowsort_kernel<<<dim3(NB, NR), dim3(256), 0, stream>>>(csr, gstart, rowptr);
        spmm_fused_kernel<<<dim3((NN * 64 + 255) / 256), dim3(256), 0, stream>>>(
            (const uint2*)xwb, csr, rowptr, b, out);
    } else {
        // sequential atomic-scatter fallback (19.2MB)
        __hip_bfloat16* xwb = (__hip_bfloat16*)ws;
        float* agg = (float*)(ws + (size_t)NN * DO * 2);
        hipMemsetAsync(agg, 0, (size_t)NN * DO * 4, stream);
        for (int r = 0; r < NR; ++r) {
            gemm_kernel<<<dim3((NN + 31) / 32), dim3(256), 0, stream>>>(
                x, W + (size_t)r * DI * DO, xwb);
            scatter_kernel<<<dim3(2048), dim3(256), 0, stream>>>(
                xwb, vals + (size_t)r * NE, rows + (size_t)r * NE,
                cols + (size_t)r * NE, agg);
            accum_kernel<<<dim3((NN * DO + 255) / 256), dim3(256), 0, stream>>>(
                agg, b + (size_t)r * DO, out, r == 0);
        }
        norm_kernel<<<dim3((NN * DO + 255) / 256), dim3(256), 0, stream>>>(out);
    }
}

// Round 10
// 178.630 us; speedup vs baseline: 2.7510x; 1.0568x over previous
//
#include <hip/hip_runtime.h>
#include <hip/hip_bf16.h>
#include <stdint.h>

#define NN 50000   // nodes
#define DI 128     // input features
#define DO 64      // output features
#define NE 800000  // edges per relation
#define NR 4       // relations
#define NB 782     // ceil(NN/64) 64-row blocks
#define NBUCK (NR*NB)   // 3128 buckets total
#define PCHUNK 7168     // edges per place workgroup
#define PWG ((NE + PCHUNK - 1) / PCHUNK)   // 112 per relation
#define RSCAP 4096      // rowsort bucket capacity (mean 1023)
#define CONVB 1024      // K1 convx blocks
#define GEMMB ((NN + 127) / 128)   // 391 gemm blocks in K2

typedef short short8 __attribute__((ext_vector_type(8)));
typedef float f32x4  __attribute__((ext_vector_type(4)));
union FragU { uint4 u; short8 s; };

__device__ __forceinline__ uint32_t bfb(float f)
{
    __hip_bfloat16 h = __float2bfloat16(f);
    return (uint32_t)*reinterpret_cast<unsigned short*>(&h);
}

// ---------------------------------------------------------------------------
// Block-wide exclusive scan of a[0..N) in LDS. BLK threads, PER elems/thread.
// ---------------------------------------------------------------------------
template<int N, int PER, int BLK>
__device__ inline void block_exscan(int* a)
{
    __shared__ int wsum[BLK / 64];
    int tid = threadIdx.x;
    int base = tid * PER;
    int v[PER]; int s = 0;
    #pragma unroll
    for (int j = 0; j < PER; ++j) {
        int idx = base + j;
        int x = (idx < N) ? a[idx] : 0;
        v[j] = s; s += x;
    }
    int lane = tid & 63, wv = tid >> 6;
    int inc = s;
    #pragma unroll
    for (int off = 1; off < 64; off <<= 1) {
        int u = __shfl_up(inc, off);
        if (lane >= off) inc += u;
    }
    if (lane == 63) wsum[wv] = inc;
    __syncthreads();
    int woff = 0;
    for (int w = 0; w < wv; ++w) woff += wsum[w];
    int tb = woff + inc - s;
    #pragma unroll
    for (int j = 0; j < PER; ++j) {
        int idx = base + j;
        if (idx < N) a[idx] = tb + v[j];
    }
}

// ---------------------------------------------------------------------------
// K1: convx (blocks [0,CONVB)) || wtrans (next 128) || bhist (next 128).
// All independent; merged to cut dispatch serialization.
// ---------------------------------------------------------------------------
__global__ __launch_bounds__(256) void prep_kernel(
    const float* __restrict__ x, const float* __restrict__ W,
    const int* __restrict__ rows,
    uint2* __restrict__ xb, uint16_t* __restrict__ wt,
    int* __restrict__ gtot)
{
    __shared__ int h[NB];
    int bid = blockIdx.x, tid = threadIdx.x;

    if (bid < CONVB) {
        // ---- convx: x f32 -> bf16 packed ----
        const int total = NN * DI / 4;
        const float4* x4 = (const float4*)x;
        for (int i = bid * 256 + tid; i < total; i += CONVB * 256) {
            float4 v = x4[i];
            uint2 o;
            o.x = bfb(v.x) | (bfb(v.y) << 16);
            o.y = bfb(v.z) | (bfb(v.w) << 16);
            xb[i] = o;
        }
    } else if (bid < CONVB + 128) {
        // ---- wtrans: W [NR][DI][DO] f32 -> Wt [NR][DO][DI] bf16 ----
        int i = (bid - CONVB) * 256 + tid;   // exactly 32768
        int r = i >> 13;
        int k = (i >> 6) & 127;
        int n = i & 63;
        wt[((size_t)(r * DO + n) << 7) + k] = (uint16_t)bfb(W[i]);
    } else {
        // ---- bhist: 32 blocks per relation ----
        int bb = bid - (CONVB + 128);
        int r = bb >> 5, sub = bb & 31;
        for (int i = tid; i < NB; i += 256) h[i] = 0;
        __syncthreads();
        const int4* rr4 = (const int4*)(rows + (size_t)r * NE);
        for (int k = sub * 256 + tid; k < NE / 4; k += 32 * 256) {
            int4 v = rr4[k];
            atomicAdd(&h[v.x >> 6], 1);
            atomicAdd(&h[v.y >> 6], 1);
            atomicAdd(&h[v.z >> 6], 1);
            atomicAdd(&h[v.w >> 6], 1);
        }
        __syncthreads();
        int* gt = gtot + r * NB;
        for (int i = tid; i < NB; i += 256)
            if (h[i]) atomicAdd(&gt[i], h[i]);
    }
}

// ---------------------------------------------------------------------------
// K2: gemm_mfma (blocks [0,GEMMB)) || bases (block GEMMB). 512 threads.
// GEMM: wave = 16-row tile; A-frag b128 per ks; B-frag from Wt; MFMA 16x16x32;
// C staged in LDS -> fully coalesced uint4 stores (contiguous 128-row slab).
// D mapping: col = lane&15, row = (lane>>4)*4 + reg  [measured m89].
// ---------------------------------------------------------------------------
__global__ __launch_bounds__(512) void gemm_bases_kernel(
    const uint4* __restrict__ xb4, const uint4* __restrict__ wt4,
    uint16_t* __restrict__ xwb,
    const int* __restrict__ gtot, int* __restrict__ gstart,
    int* __restrict__ gcur)
{
    __shared__ __align__(16) uint16_t tile[128 * 64];   // 16 KB
    __shared__ int a[NBUCK + 1];                        // 12.5 KB (bases)
    int tid = threadIdx.x;

    if (blockIdx.x == GEMMB) {
        // ---- bases: scan bucket totals -> gstart + gcur ----
        for (int i = tid; i < NBUCK + 1; i += 512)
            a[i] = (i < NBUCK) ? gtot[i] : 0;
        __syncthreads();
        block_exscan<NBUCK + 1, 7, 512>(a);
        __syncthreads();
        for (int i = tid; i < NBUCK + 1; i += 512) {
            gstart[i] = a[i];
            if (i < NBUCK) gcur[i] = a[i];
        }
        return;
    }

    // ---- gemm role ----
    int wv = __builtin_amdgcn_readfirstlane(tid >> 6);
    int lane = tid & 63;
    int n0 = blockIdx.x * 128 + wv * 16;
    int m16 = lane & 15, g = lane >> 4;
    bool act = (n0 < NN);                 // wave-uniform

    FragU af[4];
    if (act) {
        #pragma unroll
        for (int ks = 0; ks < 4; ++ks)
            af[ks].u = xb4[(size_t)(n0 + m16) * 16 + ks * 4 + g];
    }

    int rows = NN - blockIdx.x * 128; if (rows > 128) rows = 128;

    for (int r = 0; r < NR; ++r) {
        if (act) {
            #pragma unroll
            for (int ct = 0; ct < 4; ++ct) {
                f32x4 acc = {0.f, 0.f, 0.f, 0.f};
                #pragma unroll
                for (int ks = 0; ks < 4; ++ks) {
                    FragU b;
                    b.u = wt4[(size_t)((r * DO + ct * 16 + m16) * 16) + ks * 4 + g];
                    acc = __builtin_amdgcn_mfma_f32_16x16x32_bf16(
                        af[ks].s, b.s, acc, 0, 0, 0);
                }
                #pragma unroll
                for (int j = 0; j < 4; ++j)
                    tile[(wv * 16 + g * 4 + j) * 64 + ct * 16 + m16] =
                        (uint16_t)bfb(acc[j]);
            }
        }
        __syncthreads();
        uint4* dst = (uint4*)(xwb + ((size_t)r * NN + blockIdx.x * 128) * 64);
        int tot = rows * 8;               // uint4s = rows*64/8
        for (int i = tid; i < tot; i += 512)
            dst[i] = ((const uint4*)tile)[i];
        __syncthreads();
    }
}

// ---------------------------------------------------------------------------
// Placement: counting-sort a PCHUNK chunk by 64-row bucket in LDS, reserve
// global ranges, flush coalesced. Record: col:16 | rowlow:6 | bucket:10.
// ---------------------------------------------------------------------------
__global__ __launch_bounds__(512) void place_kernel(
    const int* __restrict__ rows, const int* __restrict__ cols,
    const float* __restrict__ vals, int* __restrict__ gcur,
    int2* __restrict__ csr)
{
    __shared__ int lofs[NB + 1];
    __shared__ int gbase[NB];
    __shared__ int2 stag[PCHUNK];
    int r = blockIdx.y;
    int tid = threadIdx.x;
    int e0 = blockIdx.x * PCHUNK;
    int cnt = NE - e0; if (cnt > PCHUNK) cnt = PCHUNK;
    const int*   rr = rows + (size_t)r * NE + e0;
    const int*   cc = cols + (size_t)r * NE + e0;
    const float* vv = vals + (size_t)r * NE + e0;

    for (int i = tid; i <= NB; i += 512) lofs[i] = 0;
    __syncthreads();
    for (int k = tid; k < cnt; k += 512) atomicAdd(&lofs[rr[k] >> 6], 1);
    __syncthreads();
    block_exscan<NB + 1, 2, 512>(lofs);
    __syncthreads();
    for (int b = tid; b < NB; b += 512) {
        int c = lofs[b + 1] - lofs[b];
        if (c > 0) gbase[b] = atomicAdd(&gcur[r * NB + b], c);
    }
    __syncthreads();
    for (int k = tid; k < cnt; k += 512) {
        int row = rr[k];
        int b = row >> 6;
        int slot = atomicAdd(&lofs[b], 1);
        stag[slot] = make_int2((cc[k] & 0xFFFF) | ((row & 63) << 16) | (b << 22),
                               __float_as_int(vv[k]));
    }
    __syncthreads();
    for (int i = tid; i < cnt; i += 512) {
        int2 t = stag[i];
        unsigned b2 = ((unsigned)t.x) >> 22;
        int start = b2 ? lofs[b2 - 1] : 0;
        csr[gbase[b2] + (i - start)] = t;
    }
}

// ---------------------------------------------------------------------------
// Within-bucket counting sort by row (in place) + emit per-row rowptr.
// Write-back rewrites record.x = ((r*NN + col) << 4) = uint2 offset of xw row.
// ---------------------------------------------------------------------------
__global__ __launch_bounds__(256) void rowsort_kernel(
    int2* __restrict__ csr, const int* __restrict__ gstart,
    int* __restrict__ rowptr)
{
    __shared__ int2 stag[RSCAP];
    __shared__ int cnt[64];
    __shared__ int ofs[64];
    int blk = blockIdx.x;
    int r   = blockIdx.y;
    int b   = r * NB + blk;
    int s = gstart[b], e = gstart[b + 1];
    int cntE = e - s; if (cntE > RSCAP) cntE = RSCAP;
    int tid = threadIdx.x;
    if (tid < 64) cnt[tid] = 0;
    __syncthreads();

    int2 ed[RSCAP / 256];
    #pragma unroll
    for (int j = 0; j < RSCAP / 256; ++j) {
        int i = tid + j * 256;
        if (i < cntE) {
            ed[j] = csr[s + i];
            atomicAdd(&cnt[(ed[j].x >> 16) & 63], 1);
        }
    }
    __syncthreads();
    if (tid < 64) {
        int c = cnt[tid];
        int inc = c;
        #pragma unroll
        for (int off = 1; off < 64; off <<= 1) {
            int u = __shfl_up(inc, off);
            if (tid >= off) inc += u;
        }
        ofs[tid] = inc - c;
        int n = blk * 64 + tid;
        if (n < NN) rowptr[(size_t)r * NN + n] = s + inc - c;
        if (b == NBUCK - 1 && tid == 0)
            rowptr[(size_t)NR * NN] = gstart[NBUCK];
    }
    __syncthreads();
    #pragma unroll
    for (int j = 0; j < RSCAP / 256; ++j) {
        int i = tid + j * 256;
        if (i < cntE) {
            int rl = (ed[j].x >> 16) & 63;
            int slot = atomicAdd(&ofs[rl], 1);
            stag[slot] = ed[j];
        }
    }
    __syncthreads();
    for (int i = tid; i < cntE; i += 256) {
        int2 t = stag[i];
        t.x = (r * NN + (t.x & 0xFFFF)) << 4;   // uint2-offset of xw row
        csr[s + i] = t;
    }
}

// ---------------------------------------------------------------------------
// Fused SpMM v5: quarter-wave per edge, 2-stage pipeline, padded degree
// (dege = multiple of 4; preload zero-fills val beyond deg -> no in-loop
// valid logic; pad gathers hit line 0 harmlessly).
// ---------------------------------------------------------------------------
struct Stage {
    float v[NR];
    uint2 u[NR];
};

__device__ __forceinline__ void stage_issue(
    int k, const int* dege, const int* ofsv, const float* valv,
    const uint2* __restrict__ xw2, int e4, int fq, Stage& st)
{
    #pragma unroll
    for (int r = 0; r < NR; ++r) {
        if (k < dege[r]) {                     // wave-uniform branch
            int ec = k + e4;                   // <= dege-1 <= 63
            int ofs  = __shfl(ofsv[r], ec);
            float vv = __shfl(valv[r], ec);
            st.v[r] = vv;
            st.u[r] = xw2[ofs + fq];
        } else {
            st.v[r] = 0.f;
            st.u[r] = make_uint2(0u, 0u);      // avoid 0*garbage NaN
        }
    }
}

__device__ __forceinline__ void stage_consume(const Stage& st, float a[NR][4])
{
    #pragma unroll
    for (int r = 0; r < NR; ++r) {
        float v = st.v[r];
        a[r][0] = fmaf(v, __uint_as_float(st.u[r].x << 16),          a[r][0]);
        a[r][1] = fmaf(v, __uint_as_float(st.u[r].x & 0xFFFF0000u),  a[r][1]);
        a[r][2] = fmaf(v, __uint_as_float(st.u[r].y << 16),          a[r][2]);
        a[r][3] = fmaf(v, __uint_as_float(st.u[r].y & 0xFFFF0000u),  a[r][3]);
    }
}

__global__ __launch_bounds__(256) void spmm_fused_kernel(
    const uint2* __restrict__ xw2, const int2* __restrict__ csr,
    const int* __restrict__ rowptr, const float* __restrict__ bias,
    float* __restrict__ out)
{
    int n = __builtin_amdgcn_readfirstlane(
        (int)((blockIdx.x * 256 + threadIdx.x) >> 6));
    int lane = threadIdx.x & 63;
    int e4 = lane >> 4, fq = lane & 15;
    if (n >= NN) return;

    int dege[NR]; int ofsv[NR]; float valv[NR];
    int sbeg[NR], send[NR];
    int maxdeg = 0;
    #pragma unroll
    for (int r = 0; r < NR; ++r) {
        sbeg[r] = rowptr[(size_t)r * NN + n];
        send[r] = rowptr[(size_t)r * NN + n + 1];
        int d = send[r] - sbeg[r];
        if (d > 64) d = 64;
        int2 cv = (lane < d) ? csr[sbeg[r] + lane] : make_int2(0, 0);
        ofsv[r] = cv.x;                        // precomputed uint2 offset
        valv[r] = __int_as_float(cv.y);        // 0 beyond deg
        dege[r] = (d + 3) & ~3;                // pad to multiple of 4
        maxdeg = max(maxdeg, dege[r]);
    }

    float a[NR][4];
    #pragma unroll
    for (int r = 0; r < NR; ++r)
        #pragma unroll
        for (int j = 0; j < 4; ++j) a[r][j] = 0.f;

    Stage A, B;
    stage_issue(0, dege, ofsv, valv, xw2, e4, fq, A);
    for (int k = 0; k < maxdeg; k += 8) {
        stage_issue(k + 4, dege, ofsv, valv, xw2, e4, fq, B);
        stage_consume(A, a);
        stage_issue(k + 8, dege, ofsv, valv, xw2, e4, fq, A);
        stage_consume(B, a);
    }

    // rare tail: deg > 64 (group 0 accumulates; others add 0)
    #pragma unroll
    for (int r = 0; r < NR; ++r) {
        for (int i = sbeg[r] + 64; i < send[r]; ++i) {   // ~never taken
            int2 cv = csr[i];
            float v = (lane < 16) ? __int_as_float(cv.y) : 0.f;
            uint2 u = xw2[cv.x + fq];
            a[r][0] = fmaf(v, __uint_as_float(u.x << 16),         a[r][0]);
            a[r][1] = fmaf(v, __uint_as_float(u.x & 0xFFFF0000u), a[r][1]);
            a[r][2] = fmaf(v, __uint_as_float(u.y << 16),         a[r][2]);
            a[r][3] = fmaf(v, __uint_as_float(u.y & 0xFFFF0000u), a[r][3]);
        }
    }

    // reduce over the 4 edge-groups; then bias+relu+sum across relations
    float t[4] = {0.f, 0.f, 0.f, 0.f};
    #pragma unroll
    for (int r = 0; r < NR; ++r) {
        #pragma unroll
        for (int j = 0; j < 4; ++j) {
            a[r][j] += __shfl_xor(a[r][j], 16);
            a[r][j] += __shfl_xor(a[r][j], 32);
        }
        float4 br = *(const float4*)&bias[r * DO + 4 * fq];
        t[0] += fmaxf(a[r][0] + br.x, 0.f);
        t[1] += fmaxf(a[r][1] + br.y, 0.f);
        t[2] += fmaxf(a[r][2] + br.z, 0.f);
        t[3] += fmaxf(a[r][3] + br.w, 0.f);
    }
    float s2 = t[0]*t[0] + t[1]*t[1] + t[2]*t[2] + t[3]*t[3];
    #pragma unroll
    for (int off = 8; off >= 1; off >>= 1) s2 += __shfl_xor(s2, off);
    float inv = 1.0f / fmaxf(sqrtf(s2), 1e-12f);
    if (lane < 16) {
        float4 o = make_float4(t[0]*inv, t[1]*inv, t[2]*inv, t[3]*inv);
        *(float4*)&out[(size_t)n * DO + 4 * fq] = o;
    }
}

// ---------------------------------------------------------------------------
// Fallback path (small ws): R1 atomic-scatter pipeline.
// ---------------------------------------------------------------------------
__global__ __launch_bounds__(256) void gemm_kernel(
    const float* __restrict__ x, const float* __restrict__ W,
    __hip_bfloat16* __restrict__ xwb)
{
    __shared__ float Wl[DI * DO];
    for (int i = threadIdx.x; i < DI * DO; i += 256) Wl[i] = W[i];
    __syncthreads();

    int wv   = __builtin_amdgcn_readfirstlane((int)(threadIdx.x >> 6));
    int lane = threadIdx.x & 63;
    int n0   = blockIdx.x * 32 + wv * 8;
    if (n0 >= NN) return;
    int nrows = NN - n0; if (nrows > 8) nrows = 8;

    if (nrows == 8) {
        const float* xr = x + (size_t)n0 * DI;
        float acc[8] = {0.f,0.f,0.f,0.f,0.f,0.f,0.f,0.f};
        #pragma unroll 8
        for (int k = 0; k < DI; ++k) {
            float w = Wl[k * DO + lane];
            #pragma unroll
            for (int rr = 0; rr < 8; ++rr)
                acc[rr] = fmaf(xr[(size_t)rr * DI + k], w, acc[rr]);
        }
        #pragma unroll
        for (int rr = 0; rr < 8; ++rr)
            xwb[(size_t)(n0 + rr) * DO + lane] = __float2bfloat16(acc[rr]);
    } else {
        for (int rr = 0; rr < nrows; ++rr) {
            const float* xr = x + (size_t)(n0 + rr) * DI;
            float acc = 0.f;
            for (int k = 0; k < DI; ++k)
                acc = fmaf(xr[k], Wl[k * DO + lane], acc);
            xwb[(size_t)(n0 + rr) * DO + lane] = __float2bfloat16(acc);
        }
    }
}

__global__ __launch_bounds__(256) void scatter_kernel(
    const __hip_bfloat16* __restrict__ xwb, const float* __restrict__ vals,
    const int* __restrict__ rows, const int* __restrict__ cols,
    float* __restrict__ agg)
{
    const int nPairs = NE / 2;
    int gwave  = (blockIdx.x * 256 + threadIdx.x) >> 6;
    int half   = (threadIdx.x >> 5) & 1;
    int l32    = threadIdx.x & 31;
    int stride = gridDim.x * 4;
    const uint16_t* xw16 = reinterpret_cast<const uint16_t*>(xwb);
    for (int p = gwave; p < nPairs; p += stride) {
        int e = 2 * p + half;
        int row = rows[e]; int col = cols[e]; float v = vals[e];
        uint32_t packed = *reinterpret_cast<const uint32_t*>(
            xw16 + ((size_t)col << 6) + 2 * l32);
        float f0 = __uint_as_float(packed << 16);
        float f1 = __uint_as_float(packed & 0xFFFF0000u);
        float* dst = agg + ((size_t)row << 6) + 2 * l32;
        atomicAdd(dst,     v * f0);
        atomicAdd(dst + 1, v * f1);
    }
}

__global__ __launch_bounds__(256) void accum_kernel(
    float* __restrict__ agg, const float* __restrict__ b,
    float* __restrict__ out, int first)
{
    int i = blockIdx.x * 256 + threadIdx.x;
    if (i >= NN * DO) return;
    float v = agg[i] + b[i & (DO - 1)];
    agg[i] = 0.f;
    v = fmaxf(v, 0.f);
    out[i] = first ? v : (out[i] + v);
}

__global__ __launch_bounds__(256) void norm_kernel(float* __restrict__ out)
{
    int n = (blockIdx.x * 256 + threadIdx.x) >> 6;
    int lane = threadIdx.x & 63;
    if (n >= NN) return;
    size_t idx = (size_t)n * DO + lane;
    float t = out[idx];
    float s = t * t;
    #pragma unroll
    for (int off = 32; off >= 1; off >>= 1) s += __shfl_xor(s, off);
    out[idx] = t / fmaxf(sqrtf(s), 1e-12f);
}

extern "C" void kernel_launch(void* const* d_in, const int* in_sizes, int n_in,
                              void* d_out, int out_size, void* d_ws, size_t ws_size,
                              hipStream_t stream)
{
    const float* x    = (const float*)d_in[0];
    const float* W    = (const float*)d_in[1];
    const float* b    = (const float*)d_in[2];
    const float* vals = (const float*)d_in[3];
    const int*   rows = (const int*)d_in[4];
    const int*   cols = (const int*)d_in[5];
    float* out = (float*)d_out;
    char* ws = (char*)d_ws;

    // ws: xwb 25.6MB | csr 25.6MB | rowptr 3.2MB | gtot | gstart | gcur
    // xb (12.8MB) + Wt (64KB) OVERLAY the csr region (dead before place).
    const size_t O_XW = 0;
    const size_t O_CS = O_XW + (size_t)NR * NN * DO * 2;
    const size_t O_RP = O_CS + (size_t)NR * NE * 8;
    const size_t O_GT = O_RP + ((size_t)NR * NN + 4) * 4;
    const size_t O_GS = O_GT + (size_t)NBUCK * 4;
    const size_t O_GC = O_GS + (size_t)(NBUCK + 1) * 4;
    const size_t NEED = O_GC + (size_t)NBUCK * 4;
    const size_t O_XB = O_CS;                         // bf16 x, 12.8MB
    const size_t O_WT = O_CS + 13u * 1024 * 1024;     // bf16 W^T, 64KB

    if (ws_size >= NEED) {
        __hip_bfloat16* xwb = (__hip_bfloat16*)(ws + O_XW);
        int2* csr   = (int2*)(ws + O_CS);
        int* rowptr = (int*)(ws + O_RP);
        int* gtot   = (int*)(ws + O_GT);
        int* gstart = (int*)(ws + O_GS);
        int* gcur   = (int*)(ws + O_GC);
        uint2* xb   = (uint2*)(ws + O_XB);
        uint16_t* wt = (uint16_t*)(ws + O_WT);

        hipMemsetAsync(gtot, 0, (size_t)NBUCK * 4, stream);
        prep_kernel<<<dim3(CONVB + 128 + 128), dim3(256), 0, stream>>>(
            x, W, rows, xb, wt, gtot);
        gemm_bases_kernel<<<dim3(GEMMB + 1), dim3(512), 0, stream>>>(
            (const uint4*)xb, (const uint4*)wt, (uint16_t*)xwb,
            gtot, gstart, gcur);
        place_kernel<<<dim3(PWG, NR), dim3(512), 0, stream>>>(
            rows, cols, vals, gcur, csr);
        rowsort_kernel<<<dim3(NB, NR), dim3(256), 0, stream>>>(csr, gstart, rowptr);
        spmm_fused_kernel<<<dim3((NN * 64 + 255) / 256), dim3(256), 0, stream>>>(
            (const uint2*)xwb, csr, rowptr, b, out);
    } else {
        // sequential atomic-scatter fallback (19.2MB)
        __hip_bfloat16* xwb = (__hip_bfloat16*)ws;
        float* agg = (float*)(ws + (size_t)NN * DO * 2);
        hipMemsetAsync(agg, 0, (size_t)NN * DO * 4, stream);
        for (int r = 0; r < NR; ++r) {
            gemm_kernel<<<dim3((NN + 31) / 32), dim3(256), 0, stream>>>(
                x, W + (size_t)r * DI * DO, xwb);
            scatter_kernel<<<dim3(2048), dim3(256), 0, stream>>>(
                xwb, vals + (size_t)r * NE, rows + (size_t)r * NE,
                cols + (size_t)r * NE, agg);
            accum_kernel<<<dim3((NN * DO + 255) / 256), dim3(256), 0, stream>>>(
                agg, b + (size_t)r * DO, out, r == 0);
        }
        norm_kernel<<<dim3((NN * DO + 255) / 256), dim3(256), 0, stream>>>(out);
    }
}

// Round 11
// 171.922 us; speedup vs baseline: 2.8583x; 1.0390x over previous
//
#include <hip/hip_runtime.h>
#include <hip/hip_bf16.h>
#include <stdint.h>

#define NN 50000   // nodes
#define DI 128     // input features
#define DO 64      // output features
#define NE 800000  // edges per relation
#define NR 4       // relations
#define NB 782     // ceil(NN/64) 64-row blocks
#define NBUCK (NR*NB)   // 3128 buckets total
#define PCHUNK 7168     // edges per place workgroup
#define PWG ((NE + PCHUNK - 1) / PCHUNK)   // 112 per relation
#define RSCAP 4096      // rowsort bucket capacity (mean 1023)
#define GEMMB ((NN + 127) / 128)   // 391 gemm blocks in K3

typedef short short8 __attribute__((ext_vector_type(8)));
typedef float f32x4  __attribute__((ext_vector_type(4)));
union FragU { uint4 u; short8 s; };

__device__ __forceinline__ uint32_t bfb(float f)
{
    __hip_bfloat16 h = __float2bfloat16(f);
    return (uint32_t)*reinterpret_cast<unsigned short*>(&h);
}

// ---------------------------------------------------------------------------
// Block-wide exclusive scan of a[0..N) in LDS. BLK threads, PER elems/thread.
// ---------------------------------------------------------------------------
template<int N, int PER, int BLK>
__device__ inline void block_exscan(int* a)
{
    __shared__ int wsum[BLK / 64];
    int tid = threadIdx.x;
    int base = tid * PER;
    int v[PER]; int s = 0;
    #pragma unroll
    for (int j = 0; j < PER; ++j) {
        int idx = base + j;
        int x = (idx < N) ? a[idx] : 0;
        v[j] = s; s += x;
    }
    int lane = tid & 63, wv = tid >> 6;
    int inc = s;
    #pragma unroll
    for (int off = 1; off < 64; off <<= 1) {
        int u = __shfl_up(inc, off);
        if (lane >= off) inc += u;
    }
    if (lane == 63) wsum[wv] = inc;
    __syncthreads();
    int woff = 0;
    for (int w = 0; w < wv; ++w) woff += wsum[w];
    int tb = woff + inc - s;
    #pragma unroll
    for (int j = 0; j < PER; ++j) {
        int idx = base + j;
        if (idx < N) a[idx] = tb + v[j];
    }
}

// ---------------------------------------------------------------------------
// K1: wtrans (blocks [0,128)) || bhist (blocks [128,256)).
// ---------------------------------------------------------------------------
__global__ __launch_bounds__(256) void prep_kernel(
    const float* __restrict__ W, const int* __restrict__ rows,
    uint16_t* __restrict__ wt, int* __restrict__ gtot)
{
    __shared__ int h[NB];
    int bid = blockIdx.x, tid = threadIdx.x;

    if (bid < 128) {
        // ---- wtrans: W [NR][DI][DO] f32 -> Wt [NR][DO][DI] bf16 ----
        int i = bid * 256 + tid;   // exactly 32768
        int r = i >> 13;
        int k = (i >> 6) & 127;
        int n = i & 63;
        wt[((size_t)(r * DO + n) << 7) + k] = (uint16_t)bfb(W[i]);
    } else {
        // ---- bhist: 32 blocks per relation ----
        int bb = bid - 128;
        int r = bb >> 5, sub = bb & 31;
        for (int i = tid; i < NB; i += 256) h[i] = 0;
        __syncthreads();
        const int4* rr4 = (const int4*)(rows + (size_t)r * NE);
        for (int k = sub * 256 + tid; k < NE / 4; k += 32 * 256) {
            int4 v = rr4[k];
            atomicAdd(&h[v.x >> 6], 1);
            atomicAdd(&h[v.y >> 6], 1);
            atomicAdd(&h[v.z >> 6], 1);
            atomicAdd(&h[v.w >> 6], 1);
        }
        __syncthreads();
        int* gt = gtot + r * NB;
        for (int i = tid; i < NB; i += 256)
            if (h[i]) atomicAdd(&gt[i], h[i]);
    }
}

// ---------------------------------------------------------------------------
// K2: scan bucket totals -> gstart[0..NBUCK] + gcur copy. One block.
// ---------------------------------------------------------------------------
__global__ __launch_bounds__(512) void bases_kernel(
    const int* __restrict__ gtot, int* __restrict__ gstart,
    int* __restrict__ gcur)
{
    __shared__ int a[NBUCK + 1];
    int tid = threadIdx.x;
    for (int i = tid; i < NBUCK + 1; i += 512) a[i] = (i < NBUCK) ? gtot[i] : 0;
    __syncthreads();
    block_exscan<NBUCK + 1, 7, 512>(a);
    __syncthreads();
    for (int i = tid; i < NBUCK + 1; i += 512) {
        gstart[i] = a[i];
        if (i < NBUCK) gcur[i] = a[i];
    }
}

// ---------------------------------------------------------------------------
// K3: gemm (blocks [0,GEMMB)) || place (blocks [GEMMB, GEMMB+PWG*NR)).
// Disjoint outputs (xwb vs csr); wt lives OUTSIDE the csr region.
// Shared LDS pool carved per role: place 63.6KB, gemm 16KB tile.
//
// gemm role: wave = 16 rows; x loaded f32 + converted in-register to bf16
// fragments (rounding identical to the old convx path); MFMA 16x16x32;
// C staged in LDS -> coalesced uint4 stores.
// D mapping: col = lane&15, row = (lane>>4)*4 + reg  [measured m89].
//
// place role: counting-sort a PCHUNK chunk by 64-row bucket in LDS, reserve
// global ranges, flush coalesced. Record: col:16 | rowlow:6 | bucket:10.
// ---------------------------------------------------------------------------
__global__ __launch_bounds__(512) void gemm_place_kernel(
    const float* __restrict__ x, const uint4* __restrict__ wt4,
    uint16_t* __restrict__ xwb,
    const int* __restrict__ rows, const int* __restrict__ cols,
    const float* __restrict__ vals, int* __restrict__ gcur,
    int2* __restrict__ csr)
{
    __shared__ __align__(16) char smem[63616];
    int tid = threadIdx.x;

    if (blockIdx.x < GEMMB) {
        // ================= gemm role =================
        uint16_t* tile = (uint16_t*)smem;           // 16 KB
        int wv = __builtin_amdgcn_readfirstlane(tid >> 6);
        int lane = tid & 63;
        int n0 = blockIdx.x * 128 + wv * 16;
        int m16 = lane & 15, g = lane >> 4;
        bool act = (n0 < NN);                       // wave-uniform

        FragU af[4];
        if (act) {
            const float4* x4 = (const float4*)x;
            size_t rb = ((size_t)(n0 + m16) * DI) >> 2;
            #pragma unroll
            for (int ks = 0; ks < 4; ++ks) {
                float4 f0 = x4[rb + ks * 8 + g * 2];
                float4 f1 = x4[rb + ks * 8 + g * 2 + 1];
                af[ks].u.x = bfb(f0.x) | (bfb(f0.y) << 16);
                af[ks].u.y = bfb(f0.z) | (bfb(f0.w) << 16);
                af[ks].u.z = bfb(f1.x) | (bfb(f1.y) << 16);
                af[ks].u.w = bfb(f1.z) | (bfb(f1.w) << 16);
            }
        }

        int nrows = NN - blockIdx.x * 128; if (nrows > 128) nrows = 128;

        for (int r = 0; r < NR; ++r) {
            if (act) {
                #pragma unroll
                for (int ct = 0; ct < 4; ++ct) {
                    f32x4 acc = {0.f, 0.f, 0.f, 0.f};
                    #pragma unroll
                    for (int ks = 0; ks < 4; ++ks) {
                        FragU b;
                        b.u = wt4[(size_t)((r * DO + ct * 16 + m16) * 16) + ks * 4 + g];
                        acc = __builtin_amdgcn_mfma_f32_16x16x32_bf16(
                            af[ks].s, b.s, acc, 0, 0, 0);
                    }
                    #pragma unroll
                    for (int j = 0; j < 4; ++j)
                        tile[(wv * 16 + g * 4 + j) * 64 + ct * 16 + m16] =
                            (uint16_t)bfb(acc[j]);
                }
            }
            __syncthreads();
            uint4* dst = (uint4*)(xwb + ((size_t)r * NN + blockIdx.x * 128) * 64);
            int tot = nrows * 8;
            for (int i = tid; i < tot; i += 512)
                dst[i] = ((const uint4*)tile)[i];
            __syncthreads();
        }
        return;
    }

    // ================= place role =================
    int* lofs  = (int*)smem;                        // (NB+1)*4 = 3132
    int* gbase = (int*)(smem + 3136);               // NB*4 = 3128
    int2* stag = (int2*)(smem + 6272);              // PCHUNK*8 = 57344
    int pb = blockIdx.x - GEMMB;
    int r = pb / PWG;
    int chunk = pb - r * PWG;
    int e0 = chunk * PCHUNK;
    int cnt = NE - e0; if (cnt > PCHUNK) cnt = PCHUNK;
    const int*   rr = rows + (size_t)r * NE + e0;
    const int*   cc = cols + (size_t)r * NE + e0;
    const float* vv = vals + (size_t)r * NE + e0;

    for (int i = tid; i <= NB; i += 512) lofs[i] = 0;
    __syncthreads();
    for (int k = tid; k < cnt; k += 512) atomicAdd(&lofs[rr[k] >> 6], 1);
    __syncthreads();
    block_exscan<NB + 1, 2, 512>(lofs);
    __syncthreads();
    for (int b = tid; b < NB; b += 512) {
        int c = lofs[b + 1] - lofs[b];
        if (c > 0) gbase[b] = atomicAdd(&gcur[r * NB + b], c);
    }
    __syncthreads();
    for (int k = tid; k < cnt; k += 512) {
        int row = rr[k];
        int b = row >> 6;
        int slot = atomicAdd(&lofs[b], 1);
        stag[slot] = make_int2((cc[k] & 0xFFFF) | ((row & 63) << 16) | (b << 22),
                               __float_as_int(vv[k]));
    }
    __syncthreads();
    for (int i = tid; i < cnt; i += 512) {
        int2 t = stag[i];
        unsigned b2 = ((unsigned)t.x) >> 22;
        int start = b2 ? lofs[b2 - 1] : 0;
        csr[gbase[b2] + (i - start)] = t;
    }
}

// ---------------------------------------------------------------------------
// K4: within-bucket counting sort by row (in place) + emit per-row rowptr.
// Write-back rewrites record.x = ((r*NN + col) << 4) = uint2 offset of xw row.
// ---------------------------------------------------------------------------
__global__ __launch_bounds__(256) void rowsort_kernel(
    int2* __restrict__ csr, const int* __restrict__ gstart,
    int* __restrict__ rowptr)
{
    __shared__ int2 stag[RSCAP];
    __shared__ int cnt[64];
    __shared__ int ofs[64];
    int blk = blockIdx.x;
    int r   = blockIdx.y;
    int b   = r * NB + blk;
    int s = gstart[b], e = gstart[b + 1];
    int cntE = e - s; if (cntE > RSCAP) cntE = RSCAP;
    int tid = threadIdx.x;
    if (tid < 64) cnt[tid] = 0;
    __syncthreads();

    int2 ed[RSCAP / 256];
    #pragma unroll
    for (int j = 0; j < RSCAP / 256; ++j) {
        int i = tid + j * 256;
        if (i < cntE) {
            ed[j] = csr[s + i];
            atomicAdd(&cnt[(ed[j].x >> 16) & 63], 1);
        }
    }
    __syncthreads();
    if (tid < 64) {
        int c = cnt[tid];
        int inc = c;
        #pragma unroll
        for (int off = 1; off < 64; off <<= 1) {
            int u = __shfl_up(inc, off);
            if (tid >= off) inc += u;
        }
        ofs[tid] = inc - c;
        int n = blk * 64 + tid;
        if (n < NN) rowptr[(size_t)r * NN + n] = s + inc - c;
        if (b == NBUCK - 1 && tid == 0)
            rowptr[(size_t)NR * NN] = gstart[NBUCK];
    }
    __syncthreads();
    #pragma unroll
    for (int j = 0; j < RSCAP / 256; ++j) {
        int i = tid + j * 256;
        if (i < cntE) {
            int rl = (ed[j].x >> 16) & 63;
            int slot = atomicAdd(&ofs[rl], 1);
            stag[slot] = ed[j];
        }
    }
    __syncthreads();
    for (int i = tid; i < cntE; i += 256) {
        int2 t = stag[i];
        t.x = (r * NN + (t.x & 0xFFFF)) << 4;   // uint2-offset of xw row
        csr[s + i] = t;
    }
}

// ---------------------------------------------------------------------------
// K5: fused SpMM, quarter-wave per edge, 2-stage pipeline, padded degree.
// ---------------------------------------------------------------------------
struct Stage {
    float v[NR];
    uint2 u[NR];
};

__device__ __forceinline__ void stage_issue(
    int k, const int* dege, const int* ofsv, const float* valv,
    const uint2* __restrict__ xw2, int e4, int fq, Stage& st)
{
    #pragma unroll
    for (int r = 0; r < NR; ++r) {
        if (k < dege[r]) {                     // wave-uniform branch
            int ec = k + e4;                   // <= dege-1 <= 63
            int ofs  = __shfl(ofsv[r], ec);
            float vv = __shfl(valv[r], ec);
            st.v[r] = vv;
            st.u[r] = xw2[ofs + fq];
        } else {
            st.v[r] = 0.f;
            st.u[r] = make_uint2(0u, 0u);      // avoid 0*garbage NaN
        }
    }
}

__device__ __forceinline__ void stage_consume(const Stage& st, float a[NR][4])
{
    #pragma unroll
    for (int r = 0; r < NR; ++r) {
        float v = st.v[r];
        a[r][0] = fmaf(v, __uint_as_float(st.u[r].x << 16),          a[r][0]);
        a[r][1] = fmaf(v, __uint_as_float(st.u[r].x & 0xFFFF0000u),  a[r][1]);
        a[r][2] = fmaf(v, __uint_as_float(st.u[r].y << 16),          a[r][2]);
        a[r][3] = fmaf(v, __uint_as_float(st.u[r].y & 0xFFFF0000u),  a[r][3]);
    }
}

__global__ __launch_bounds__(256) void spmm_fused_kernel(
    const uint2* __restrict__ xw2, const int2* __restrict__ csr,
    const int* __restrict__ rowptr, const float* __restrict__ bias,
    float* __restrict__ out)
{
    int n = __builtin_amdgcn_readfirstlane(
        (int)((blockIdx.x * 256 + threadIdx.x) >> 6));
    int lane = threadIdx.x & 63;
    int e4 = lane >> 4, fq = lane & 15;
    if (n >= NN) return;

    int dege[NR]; int ofsv[NR]; float valv[NR];
    int sbeg[NR], send[NR];
    int maxdeg = 0;
    #pragma unroll
    for (int r = 0; r < NR; ++r) {
        sbeg[r] = rowptr[(size_t)r * NN + n];
        send[r] = rowptr[(size_t)r * NN + n + 1];
        int d = send[r] - sbeg[r];
        if (d > 64) d = 64;
        int2 cv = (lane < d) ? csr[sbeg[r] + lane] : make_int2(0, 0);
        ofsv[r] = cv.x;                        // precomputed uint2 offset
        valv[r] = __int_as_float(cv.y);        // 0 beyond deg
        dege[r] = (d + 3) & ~3;                // pad to multiple of 4
        maxdeg = max(maxdeg, dege[r]);
    }

    float a[NR][4];
    #pragma unroll
    for (int r = 0; r < NR; ++r)
        #pragma unroll
        for (int j = 0; j < 4; ++j) a[r][j] = 0.f;

    Stage A, B;
    stage_issue(0, dege, ofsv, valv, xw2, e4, fq, A);
    for (int k = 0; k < maxdeg; k += 8) {
        stage_issue(k + 4, dege, ofsv, valv, xw2, e4, fq, B);
        stage_consume(A, a);
        stage_issue(k + 8, dege, ofsv, valv, xw2, e4, fq, A);
        stage_consume(B, a);
    }

    // rare tail: deg > 64 (group 0 accumulates; others add 0)
    #pragma unroll
    for (int r = 0; r < NR; ++r) {
        for (int i = sbeg[r] + 64; i < send[r]; ++i) {   // ~never taken
            int2 cv = csr[i];
            float v = (lane < 16) ? __int_as_float(cv.y) : 0.f;
            uint2 u = xw2[cv.x + fq];
            a[r][0] = fmaf(v, __uint_as_float(u.x << 16),         a[r][0]);
            a[r][1] = fmaf(v, __uint_as_float(u.x & 0xFFFF0000u), a[r][1]);
            a[r][2] = fmaf(v, __uint_as_float(u.y << 16),         a[r][2]);
            a[r][3] = fmaf(v, __uint_as_float(u.y & 0xFFFF0000u), a[r][3]);
        }
    }

    // reduce over the 4 edge-groups; then bias+relu+sum across relations
    float t[4] = {0.f, 0.f, 0.f, 0.f};
    #pragma unroll
    for (int r = 0; r < NR; ++r) {
        #pragma unroll
        for (int j = 0; j < 4; ++j) {
            a[r][j] += __shfl_xor(a[r][j], 16);
            a[r][j] += __shfl_xor(a[r][j], 32);
        }
        float4 br = *(const float4*)&bias[r * DO + 4 * fq];
        t[0] += fmaxf(a[r][0] + br.x, 0.f);
        t[1] += fmaxf(a[r][1] + br.y, 0.f);
        t[2] += fmaxf(a[r][2] + br.z, 0.f);
        t[3] += fmaxf(a[r][3] + br.w, 0.f);
    }
    float s2 = t[0]*t[0] + t[1]*t[1] + t[2]*t[2] + t[3]*t[3];
    #pragma unroll
    for (int off = 8; off >= 1; off >>= 1) s2 += __shfl_xor(s2, off);
    float inv = 1.0f / fmaxf(sqrtf(s2), 1e-12f);
    if (lane < 16) {
        float4 o = make_float4(t[0]*inv, t[1]*inv, t[2]*inv, t[3]*inv);
        *(float4*)&out[(size_t)n * DO + 4 * fq] = o;
    }
}

// ---------------------------------------------------------------------------
// Fallback path (small ws): R1 atomic-scatter pipeline.
// ---------------------------------------------------------------------------
__global__ __launch_bounds__(256) void gemm_kernel(
    const float* __restrict__ x, const float* __restrict__ W,
    __hip_bfloat16* __restrict__ xwb)
{
    __shared__ float Wl[DI * DO];
    for (int i = threadIdx.x; i < DI * DO; i += 256) Wl[i] = W[i];
    __syncthreads();

    int wv   = __builtin_amdgcn_readfirstlane((int)(threadIdx.x >> 6));
    int lane = threadIdx.x & 63;
    int n0   = blockIdx.x * 32 + wv * 8;
    if (n0 >= NN) return;
    int nrows = NN - n0; if (nrows > 8) nrows = 8;

    if (nrows == 8) {
        const float* xr = x + (size_t)n0 * DI;
        float acc[8] = {0.f,0.f,0.f,0.f,0.f,0.f,0.f,0.f};
        #pragma unroll 8
        for (int k = 0; k < DI; ++k) {
            float w = Wl[k * DO + lane];
            #pragma unroll
            for (int rr = 0; rr < 8; ++rr)
                acc[rr] = fmaf(xr[(size_t)rr * DI + k], w, acc[rr]);
        }
        #pragma unroll
        for (int rr = 0; rr < 8; ++rr)
            xwb[(size_t)(n0 + rr) * DO + lane] = __float2bfloat16(acc[rr]);
    } else {
        for (int rr = 0; rr < nrows; ++rr) {
            const float* xr = x + (size_t)(n0 + rr) * DI;
            float acc = 0.f;
            for (int k = 0; k < DI; ++k)
                acc = fmaf(xr[k], Wl[k * DO + lane], acc);
            xwb[(size_t)(n0 + rr) * DO + lane] = __float2bfloat16(acc);
        }
    }
}

__global__ __launch_bounds__(256) void scatter_kernel(
    const __hip_bfloat16* __restrict__ xwb, const float* __restrict__ vals,
    const int* __restrict__ rows, const int* __restrict__ cols,
    float* __restrict__ agg)
{
    const int nPairs = NE / 2;
    int gwave  = (blockIdx.x * 256 + threadIdx.x) >> 6;
    int half   = (threadIdx.x >> 5) & 1;
    int l32    = threadIdx.x & 31;
    int stride = gridDim.x * 4;
    const uint16_t* xw16 = reinterpret_cast<const uint16_t*>(xwb);
    for (int p = gwave; p < nPairs; p += stride) {
        int e = 2 * p + half;
        int row = rows[e]; int col = cols[e]; float v = vals[e];
        uint32_t packed = *reinterpret_cast<const uint32_t*>(
            xw16 + ((size_t)col << 6) + 2 * l32);
        float f0 = __uint_as_float(packed << 16);
        float f1 = __uint_as_float(packed & 0xFFFF0000u);
        float* dst = agg + ((size_t)row << 6) + 2 * l32;
        atomicAdd(dst,     v * f0);
        atomicAdd(dst + 1, v * f1);
    }
}

__global__ __launch_bounds__(256) void accum_kernel(
    float* __restrict__ agg, const float* __restrict__ b,
    float* __restrict__ out, int first)
{
    int i = blockIdx.x * 256 + threadIdx.x;
    if (i >= NN * DO) return;
    float v = agg[i] + b[i & (DO - 1)];
    agg[i] = 0.f;
    v = fmaxf(v, 0.f);
    out[i] = first ? v : (out[i] + v);
}

__global__ __launch_bounds__(256) void norm_kernel(float* __restrict__ out)
{
    int n = (blockIdx.x * 256 + threadIdx.x) >> 6;
    int lane = threadIdx.x & 63;
    if (n >= NN) return;
    size_t idx = (size_t)n * DO + lane;
    float t = out[idx];
    float s = t * t;
    #pragma unroll
    for (int off = 32; off >= 1; off >>= 1) s += __shfl_xor(s, off);
    out[idx] = t / fmaxf(sqrtf(s), 1e-12f);
}

extern "C" void kernel_launch(void* const* d_in, const int* in_sizes, int n_in,
                              void* d_out, int out_size, void* d_ws, size_t ws_size,
                              hipStream_t stream)
{
    const float* x    = (const float*)d_in[0];
    const float* W    = (const float*)d_in[1];
    const float* b    = (const float*)d_in[2];
    const float* vals = (const float*)d_in[3];
    const int*   rows = (const int*)d_in[4];
    const int*   cols = (const int*)d_in[5];
    float* out = (float*)d_out;
    char* ws = (char*)d_ws;

    // ws: xwb 25.6MB | csr 25.6MB | rowptr 3.2MB | gtot | gstart | gcur | wt
    const size_t O_XW = 0;
    const size_t O_CS = O_XW + (size_t)NR * NN * DO * 2;
    const size_t O_RP = O_CS + (size_t)NR * NE * 8;
    const size_t O_GT = O_RP + ((size_t)NR * NN + 4) * 4;
    const size_t O_GS = O_GT + (size_t)NBUCK * 4;
    const size_t O_GC = O_GS + (size_t)(NBUCK + 1) * 4;
    const size_t O_WT = O_GC + (size_t)NBUCK * 4;     // bf16 W^T, 64KB (NOT overlaid)
    const size_t NEED = O_WT + 65536;

    if (ws_size >= NEED) {
        __hip_bfloat16* xwb = (__hip_bfloat16*)(ws + O_XW);
        int2* csr   = (int2*)(ws + O_CS);
        int* rowptr = (int*)(ws + O_RP);
        int* gtot   = (int*)(ws + O_GT);
        int* gstart = (int*)(ws + O_GS);
        int* gcur   = (int*)(ws + O_GC);
        uint16_t* wt = (uint16_t*)(ws + O_WT);

        hipMemsetAsync(gtot, 0, (size_t)NBUCK * 4, stream);
        prep_kernel<<<dim3(256), dim3(256), 0, stream>>>(W, rows, wt, gtot);
        bases_kernel<<<dim3(1), dim3(512), 0, stream>>>(gtot, gstart, gcur);
        gemm_place_kernel<<<dim3(GEMMB + PWG * NR), dim3(512), 0, stream>>>(
            x, (const uint4*)wt, (uint16_t*)xwb,
            rows, cols, vals, gcur, csr);
        rowsort_kernel<<<dim3(NB, NR), dim3(256), 0, stream>>>(csr, gstart, rowptr);
        spmm_fused_kernel<<<dim3((NN * 64 + 255) / 256), dim3(256), 0, stream>>>(
            (const uint2*)xwb, csr, rowptr, b, out);
    } else {
        // sequential atomic-scatter fallback (19.2MB)
        __hip_bfloat16* xwb = (__hip_bfloat16*)ws;
        float* agg = (float*)(ws + (size_t)NN * DO * 2);
        hipMemsetAsync(agg, 0, (size_t)NN * DO * 4, stream);
        for (int r = 0; r < NR; ++r) {
            gemm_kernel<<<dim3((NN + 31) / 32), dim3(256), 0, stream>>>(
                x, W + (size_t)r * DI * DO, xwb);
            scatter_kernel<<<dim3(2048), dim3(256), 0, stream>>>(
                xwb, vals + (size_t)r * NE, rows + (size_t)r * NE,
                cols + (size_t)r * NE, agg);
            accum_kernel<<<dim3((NN * DO + 255) / 256), dim3(256), 0, stream>>>(
                agg, b + (size_t)r * DO, out, r == 0);
        }
        norm_kernel<<<dim3((NN * DO + 255) / 256), dim3(256), 0, stream>>>(out);
    }
}

// Round 12
// 162.677 us; speedup vs baseline: 3.0208x; 1.0568x over previous
//
#include <hip/hip_runtime.h>
#include <hip/hip_bf16.h>
#include <stdint.h>

#define NN 50000   // nodes
#define DI 128     // input features
#define DO 64      // output features
#define NE 800000  // edges per relation
#define NR 4       // relations
#define NB 782     // ceil(NN/64) 64-row blocks
#define NBUCK (NR*NB)   // 3128 buckets total
#define PCHUNK 7168     // edges per place workgroup
#define PWG ((NE + PCHUNK - 1) / PCHUNK)   // 112 per relation
#define GEMMB ((NN + 127) / 128)   // 391 gemm blocks
#define ECAP 1408       // spmm2 per-relation bucket-run capacity (mean 1024, +12 sigma)

typedef short short8 __attribute__((ext_vector_type(8)));
typedef float f32x4  __attribute__((ext_vector_type(4)));
union FragU { uint4 u; short8 s; };

__device__ __forceinline__ uint32_t bfb(float f)
{
    __hip_bfloat16 h = __float2bfloat16(f);
    return (uint32_t)*reinterpret_cast<unsigned short*>(&h);
}

// ---------------------------------------------------------------------------
// Block-wide exclusive scan of a[0..N) in LDS. BLK threads, PER elems/thread.
// ---------------------------------------------------------------------------
template<int N, int PER, int BLK>
__device__ inline void block_exscan(int* a)
{
    __shared__ int wsum[BLK / 64];
    int tid = threadIdx.x;
    int base = tid * PER;
    int v[PER]; int s = 0;
    #pragma unroll
    for (int j = 0; j < PER; ++j) {
        int idx = base + j;
        int x = (idx < N) ? a[idx] : 0;
        v[j] = s; s += x;
    }
    int lane = tid & 63, wv = tid >> 6;
    int inc = s;
    #pragma unroll
    for (int off = 1; off < 64; off <<= 1) {
        int u = __shfl_up(inc, off);
        if (lane >= off) inc += u;
    }
    if (lane == 63) wsum[wv] = inc;
    __syncthreads();
    int woff = 0;
    for (int w = 0; w < wv; ++w) woff += wsum[w];
    int tb = woff + inc - s;
    #pragma unroll
    for (int j = 0; j < PER; ++j) {
        int idx = base + j;
        if (idx < N) a[idx] = tb + v[j];
    }
}

// ---------------------------------------------------------------------------
// K1: wtrans (blocks [0,128)) || bhist (blocks [128,256)).
// ---------------------------------------------------------------------------
__global__ __launch_bounds__(256) void prep_kernel(
    const float* __restrict__ W, const int* __restrict__ rows,
    uint16_t* __restrict__ wt, int* __restrict__ gtot)
{
    __shared__ int h[NB];
    int bid = blockIdx.x, tid = threadIdx.x;

    if (bid < 128) {
        int i = bid * 256 + tid;   // exactly 32768
        int r = i >> 13;
        int k = (i >> 6) & 127;
        int n = i & 63;
        wt[((size_t)(r * DO + n) << 7) + k] = (uint16_t)bfb(W[i]);
    } else {
        int bb = bid - 128;
        int r = bb >> 5, sub = bb & 31;
        for (int i = tid; i < NB; i += 256) h[i] = 0;
        __syncthreads();
        const int4* rr4 = (const int4*)(rows + (size_t)r * NE);
        for (int k = sub * 256 + tid; k < NE / 4; k += 32 * 256) {
            int4 v = rr4[k];
            atomicAdd(&h[v.x >> 6], 1);
            atomicAdd(&h[v.y >> 6], 1);
            atomicAdd(&h[v.z >> 6], 1);
            atomicAdd(&h[v.w >> 6], 1);
        }
        __syncthreads();
        int* gt = gtot + r * NB;
        for (int i = tid; i < NB; i += 256)
            if (h[i]) atomicAdd(&gt[i], h[i]);
    }
}

// ---------------------------------------------------------------------------
// K2: scan bucket totals -> gstart[0..NBUCK] + gcur copy. One block.
// ---------------------------------------------------------------------------
__global__ __launch_bounds__(512) void bases_kernel(
    const int* __restrict__ gtot, int* __restrict__ gstart,
    int* __restrict__ gcur)
{
    __shared__ int a[NBUCK + 1];
    int tid = threadIdx.x;
    for (int i = tid; i < NBUCK + 1; i += 512) a[i] = (i < NBUCK) ? gtot[i] : 0;
    __syncthreads();
    block_exscan<NBUCK + 1, 7, 512>(a);
    __syncthreads();
    for (int i = tid; i < NBUCK + 1; i += 512) {
        gstart[i] = a[i];
        if (i < NBUCK) gcur[i] = a[i];
    }
}

// ---------------------------------------------------------------------------
// K3: gemm (blocks [0,GEMMB)) || place (blocks [GEMMB, GEMMB+PWG*NR)).
// gemm: x f32 -> bf16 fragments in-register; MFMA 16x16x32; LDS-staged stores.
// place: bucket counting-sort of a PCHUNK chunk; record col:16|rowlow:6|bkt:10.
// ---------------------------------------------------------------------------
__global__ __launch_bounds__(512) void gemm_place_kernel(
    const float* __restrict__ x, const uint4* __restrict__ wt4,
    uint16_t* __restrict__ xwb,
    const int* __restrict__ rows, const int* __restrict__ cols,
    const float* __restrict__ vals, int* __restrict__ gcur,
    int2* __restrict__ csr)
{
    __shared__ __align__(16) char smem[63616];
    int tid = threadIdx.x;

    if (blockIdx.x < GEMMB) {
        // ================= gemm role =================
        uint16_t* tile = (uint16_t*)smem;           // 16 KB
        int wv = __builtin_amdgcn_readfirstlane(tid >> 6);
        int lane = tid & 63;
        int n0 = blockIdx.x * 128 + wv * 16;
        int m16 = lane & 15, g = lane >> 4;
        bool act = (n0 < NN);                       // wave-uniform

        FragU af[4];
        if (act) {
            const float4* x4 = (const float4*)x;
            size_t rb = ((size_t)(n0 + m16) * DI) >> 2;
            #pragma unroll
            for (int ks = 0; ks < 4; ++ks) {
                float4 f0 = x4[rb + ks * 8 + g * 2];
                float4 f1 = x4[rb + ks * 8 + g * 2 + 1];
                af[ks].u.x = bfb(f0.x) | (bfb(f0.y) << 16);
                af[ks].u.y = bfb(f0.z) | (bfb(f0.w) << 16);
                af[ks].u.z = bfb(f1.x) | (bfb(f1.y) << 16);
                af[ks].u.w = bfb(f1.z) | (bfb(f1.w) << 16);
            }
        }

        int nrows = NN - blockIdx.x * 128; if (nrows > 128) nrows = 128;

        for (int r = 0; r < NR; ++r) {
            if (act) {
                #pragma unroll
                for (int ct = 0; ct < 4; ++ct) {
                    f32x4 acc = {0.f, 0.f, 0.f, 0.f};
                    #pragma unroll
                    for (int ks = 0; ks < 4; ++ks) {
                        FragU b;
                        b.u = wt4[(size_t)((r * DO + ct * 16 + m16) * 16) + ks * 4 + g];
                        acc = __builtin_amdgcn_mfma_f32_16x16x32_bf16(
                            af[ks].s, b.s, acc, 0, 0, 0);
                    }
                    #pragma unroll
                    for (int j = 0; j < 4; ++j)
                        tile[(wv * 16 + g * 4 + j) * 64 + ct * 16 + m16] =
                            (uint16_t)bfb(acc[j]);
                }
            }
            __syncthreads();
            uint4* dst = (uint4*)(xwb + ((size_t)r * NN + blockIdx.x * 128) * 64);
            int tot = nrows * 8;
            for (int i = tid; i < tot; i += 512)
                dst[i] = ((const uint4*)tile)[i];
            __syncthreads();
        }
        return;
    }

    // ================= place role =================
    int* lofs  = (int*)smem;                        // (NB+1)*4 = 3132
    int* gbase = (int*)(smem + 3136);               // NB*4 = 3128
    int2* stag = (int2*)(smem + 6272);              // PCHUNK*8 = 57344
    int pb = blockIdx.x - GEMMB;
    int r = pb / PWG;
    int chunk = pb - r * PWG;
    int e0 = chunk * PCHUNK;
    int cnt = NE - e0; if (cnt > PCHUNK) cnt = PCHUNK;
    const int*   rr = rows + (size_t)r * NE + e0;
    const int*   cc = cols + (size_t)r * NE + e0;
    const float* vv = vals + (size_t)r * NE + e0;

    for (int i = tid; i <= NB; i += 512) lofs[i] = 0;
    __syncthreads();
    for (int k = tid; k < cnt; k += 512) atomicAdd(&lofs[rr[k] >> 6], 1);
    __syncthreads();
    block_exscan<NB + 1, 2, 512>(lofs);
    __syncthreads();
    for (int b = tid; b < NB; b += 512) {
        int c = lofs[b + 1] - lofs[b];
        if (c > 0) gbase[b] = atomicAdd(&gcur[r * NB + b], c);
    }
    __syncthreads();
    for (int k = tid; k < cnt; k += 512) {
        int row = rr[k];
        int b = row >> 6;
        int slot = atomicAdd(&lofs[b], 1);
        stag[slot] = make_int2((cc[k] & 0xFFFF) | ((row & 63) << 16) | (b << 22),
                               __float_as_int(vv[k]));
    }
    __syncthreads();
    for (int i = tid; i < cnt; i += 512) {
        int2 t = stag[i];
        unsigned b2 = ((unsigned)t.x) >> 22;
        int start = b2 ? lofs[b2 - 1] : 0;
        csr[gbase[b2] + (i - start)] = t;
    }
}

// ---------------------------------------------------------------------------
// K4: spmm2 — bucket-resident fused rowsort + SpMM + epilogue.
// Block = 64-row bucket, 512 thr (8 waves). Stages the bucket's 4 relation
// runs into LDS (counting-sorted by row, records rewritten to precomputed
// gather offsets), then each wave processes 8 rows: quarter-wave per edge,
// 2-stage pipeline, metadata from LDS, fused bias/relu/sum/L2-normalize.
// ---------------------------------------------------------------------------
__global__ __launch_bounds__(512) void spmm2_kernel(
    const uint2* __restrict__ xw2, const int2* __restrict__ csr,
    const int* __restrict__ gstart, const float* __restrict__ bias,
    float* __restrict__ out)
{
    __shared__ int2 ebuf[NR][ECAP];     // 45056 B
    __shared__ int rcnt[NR][64];
    __shared__ int rofs[NR][64];
    __shared__ int rcur[NR][64];
    int tid = threadIdx.x, blk = blockIdx.x;
    int wv = __builtin_amdgcn_readfirstlane(tid >> 6);
    int lane = tid & 63;

    if (tid < 256) rcnt[tid >> 6][tid & 63] = 0;
    __syncthreads();

    // ---- load runs into registers + row histogram ----
    int sbeg[NR], cnt[NR], scnt[NR];
    int2 ed[NR][3];                     // ceil(ECAP/512)=3 per relation
    #pragma unroll
    for (int r = 0; r < NR; ++r) {
        int b = r * NB + blk;
        sbeg[r] = gstart[b];
        cnt[r]  = gstart[b + 1] - sbeg[r];
        scnt[r] = cnt[r] > ECAP ? ECAP : cnt[r];
        #pragma unroll
        for (int j = 0; j < 3; ++j) {
            int i = tid + j * 512;
            if (i < scnt[r]) {
                ed[r][j] = csr[sbeg[r] + i];
                atomicAdd(&rcnt[r][(ed[r][j].x >> 16) & 63], 1);
            }
        }
    }
    __syncthreads();

    // ---- per-relation 64-bin exscan (wave r handles relation r) ----
    if (wv < NR) {
        int c = rcnt[wv][lane];         // lanes 0..63 = rows
        int inc = c;
        #pragma unroll
        for (int off = 1; off < 64; off <<= 1) {
            int u = __shfl_up(inc, off);
            if (lane >= off) inc += u;
        }
        rofs[wv][lane] = inc - c;
        rcur[wv][lane] = inc - c;
    }
    __syncthreads();

    // ---- scatter into ebuf row-sorted, rewriting to gather offsets ----
    #pragma unroll
    for (int r = 0; r < NR; ++r) {
        #pragma unroll
        for (int j = 0; j < 3; ++j) {
            int i = tid + j * 512;
            if (i < scnt[r]) {
                int rl = (ed[r][j].x >> 16) & 63;
                int slot = atomicAdd(&rcur[r][rl], 1);
                ebuf[r][slot] = make_int2((r * NN + (ed[r][j].x & 0xFFFF)) << 4,
                                          ed[r][j].y);
            }
        }
    }
    __syncthreads();

    // ---- SpMM: wave wv processes rows wv*8 .. wv*8+7 ----
    int e4 = lane >> 4, fq = lane & 15;
    float4 br[NR];
    #pragma unroll
    for (int r = 0; r < NR; ++r)
        br[r] = *(const float4*)&bias[r * DO + 4 * fq];

    for (int mi = 0; mi < 8; ++mi) {
        int m = wv * 8 + mi;
        int n = blk * 64 + m;
        if (n >= NN) break;             // wave-uniform

        int st[NR], dc[NR], dege[NR];
        int maxdeg = 0;
        #pragma unroll
        for (int r = 0; r < NR; ++r) {
            st[r] = rofs[r][m];
            dc[r] = rcnt[r][m];
            dege[r] = (dc[r] + 3) & ~3;
            maxdeg = max(maxdeg, dege[r]);
        }

        float a[NR][4];
        #pragma unroll
        for (int r = 0; r < NR; ++r)
            #pragma unroll
            for (int j = 0; j < 4; ++j) a[r][j] = 0.f;

        float vA[NR]; uint2 uA[NR];
        float vB[NR]; uint2 uB[NR];

        // stage issue k=0 into A
        #pragma unroll
        for (int r = 0; r < NR; ++r) {
            if (0 < dege[r]) {
                int e = e4; int ec = e < dc[r] ? e : dc[r] - 1;
                int2 cv = ebuf[r][st[r] + ec];
                vA[r] = (e < dc[r]) ? __int_as_float(cv.y) : 0.f;
                uA[r] = xw2[cv.x + fq];
            } else { vA[r] = 0.f; uA[r] = make_uint2(0u, 0u); }
        }
        for (int k = 0; k < maxdeg; k += 8) {
            #pragma unroll
            for (int r = 0; r < NR; ++r) {          // issue k+4 -> B
                int kk = k + 4;
                if (kk < dege[r]) {
                    int e = kk + e4; int ec = e < dc[r] ? e : dc[r] - 1;
                    int2 cv = ebuf[r][st[r] + ec];
                    vB[r] = (e < dc[r]) ? __int_as_float(cv.y) : 0.f;
                    uB[r] = xw2[cv.x + fq];
                } else { vB[r] = 0.f; uB[r] = make_uint2(0u, 0u); }
            }
            #pragma unroll
            for (int r = 0; r < NR; ++r) {          // consume A
                float v = vA[r];
                a[r][0] = fmaf(v, __uint_as_float(uA[r].x << 16),         a[r][0]);
                a[r][1] = fmaf(v, __uint_as_float(uA[r].x & 0xFFFF0000u), a[r][1]);
                a[r][2] = fmaf(v, __uint_as_float(uA[r].y << 16),         a[r][2]);
                a[r][3] = fmaf(v, __uint_as_float(uA[r].y & 0xFFFF0000u), a[r][3]);
            }
            #pragma unroll
            for (int r = 0; r < NR; ++r) {          // issue k+8 -> A
                int kk = k + 8;
                if (kk < dege[r]) {
                    int e = kk + e4; int ec = e < dc[r] ? e : dc[r] - 1;
                    int2 cv = ebuf[r][st[r] + ec];
                    vA[r] = (e < dc[r]) ? __int_as_float(cv.y) : 0.f;
                    uA[r] = xw2[cv.x + fq];
                } else { vA[r] = 0.f; uA[r] = make_uint2(0u, 0u); }
            }
            #pragma unroll
            for (int r = 0; r < NR; ++r) {          // consume B
                float v = vB[r];
                a[r][0] = fmaf(v, __uint_as_float(uB[r].x << 16),         a[r][0]);
                a[r][1] = fmaf(v, __uint_as_float(uB[r].x & 0xFFFF0000u), a[r][1]);
                a[r][2] = fmaf(v, __uint_as_float(uB[r].y << 16),         a[r][2]);
                a[r][3] = fmaf(v, __uint_as_float(uB[r].y & 0xFFFF0000u), a[r][3]);
            }
        }

        // overflow tail (cnt>ECAP: ~never; scan unstaged edges from global)
        #pragma unroll
        for (int r = 0; r < NR; ++r) {
            if (cnt[r] > ECAP) {                    // wave-uniform
                for (int i = sbeg[r] + ECAP; i < sbeg[r] + cnt[r]; ++i) {
                    int2 cv = csr[i];
                    int rl = (cv.x >> 16) & 63;
                    float v = (rl == m && lane < 16) ? __int_as_float(cv.y) : 0.f;
                    uint2 u = xw2[(((size_t)r * NN + (cv.x & 0xFFFF)) << 4) + fq];
                    a[r][0] = fmaf(v, __uint_as_float(u.x << 16),         a[r][0]);
                    a[r][1] = fmaf(v, __uint_as_float(u.x & 0xFFFF0000u), a[r][1]);
                    a[r][2] = fmaf(v, __uint_as_float(u.y << 16),         a[r][2]);
                    a[r][3] = fmaf(v, __uint_as_float(u.y & 0xFFFF0000u), a[r][3]);
                }
            }
        }

        // epilogue: reduce edge-groups, bias+relu+sum, L2 normalize
        float t[4] = {0.f, 0.f, 0.f, 0.f};
        #pragma unroll
        for (int r = 0; r < NR; ++r) {
            #pragma unroll
            for (int j = 0; j < 4; ++j) {
                a[r][j] += __shfl_xor(a[r][j], 16);
                a[r][j] += __shfl_xor(a[r][j], 32);
            }
            t[0] += fmaxf(a[r][0] + br[r].x, 0.f);
            t[1] += fmaxf(a[r][1] + br[r].y, 0.f);
            t[2] += fmaxf(a[r][2] + br[r].z, 0.f);
            t[3] += fmaxf(a[r][3] + br[r].w, 0.f);
        }
        float s2 = t[0]*t[0] + t[1]*t[1] + t[2]*t[2] + t[3]*t[3];
        #pragma unroll
        for (int off = 8; off >= 1; off >>= 1) s2 += __shfl_xor(s2, off);
        float inv = 1.0f / fmaxf(sqrtf(s2), 1e-12f);
        if (lane < 16) {
            float4 o = make_float4(t[0]*inv, t[1]*inv, t[2]*inv, t[3]*inv);
            *(float4*)&out[(size_t)n * DO + 4 * fq] = o;
        }
    }
}

// ---------------------------------------------------------------------------
// Fallback path (small ws): R1 atomic-scatter pipeline.
// ---------------------------------------------------------------------------
__global__ __launch_bounds__(256) void gemm_kernel(
    const float* __restrict__ x, const float* __restrict__ W,
    __hip_bfloat16* __restrict__ xwb)
{
    __shared__ float Wl[DI * DO];
    for (int i = threadIdx.x; i < DI * DO; i += 256) Wl[i] = W[i];
    __syncthreads();

    int wv   = __builtin_amdgcn_readfirstlane((int)(threadIdx.x >> 6));
    int lane = threadIdx.x & 63;
    int n0   = blockIdx.x * 32 + wv * 8;
    if (n0 >= NN) return;
    int nrows = NN - n0; if (nrows > 8) nrows = 8;

    if (nrows == 8) {
        const float* xr = x + (size_t)n0 * DI;
        float acc[8] = {0.f,0.f,0.f,0.f,0.f,0.f,0.f,0.f};
        #pragma unroll 8
        for (int k = 0; k < DI; ++k) {
            float w = Wl[k * DO + lane];
            #pragma unroll
            for (int rr = 0; rr < 8; ++rr)
                acc[rr] = fmaf(xr[(size_t)rr * DI + k], w, acc[rr]);
        }
        #pragma unroll
        for (int rr = 0; rr < 8; ++rr)
            xwb[(size_t)(n0 + rr) * DO + lane] = __float2bfloat16(acc[rr]);
    } else {
        for (int rr = 0; rr < nrows; ++rr) {
            const float* xr = x + (size_t)(n0 + rr) * DI;
            float acc = 0.f;
            for (int k = 0; k < DI; ++k)
                acc = fmaf(xr[k], Wl[k * DO + lane], acc);
            xwb[(size_t)(n0 + rr) * DO + lane] = __float2bfloat16(acc);
        }
    }
}

__global__ __launch_bounds__(256) void scatter_kernel(
    const __hip_bfloat16* __restrict__ xwb, const float* __restrict__ vals,
    const int* __restrict__ rows, const int* __restrict__ cols,
    float* __restrict__ agg)
{
    const int nPairs = NE / 2;
    int gwave  = (blockIdx.x * 256 + threadIdx.x) >> 6;
    int half   = (threadIdx.x >> 5) & 1;
    int l32    = threadIdx.x & 31;
    int stride = gridDim.x * 4;
    const uint16_t* xw16 = reinterpret_cast<const uint16_t*>(xwb);
    for (int p = gwave; p < nPairs; p += stride) {
        int e = 2 * p + half;
        int row = rows[e]; int col = cols[e]; float v = vals[e];
        uint32_t packed = *reinterpret_cast<const uint32_t*>(
            xw16 + ((size_t)col << 6) + 2 * l32);
        float f0 = __uint_as_float(packed << 16);
        float f1 = __uint_as_float(packed & 0xFFFF0000u);
        float* dst = agg + ((size_t)row << 6) + 2 * l32;
        atomicAdd(dst,     v * f0);
        atomicAdd(dst + 1, v * f1);
    }
}

__global__ __launch_bounds__(256) void accum_kernel(
    float* __restrict__ agg, const float* __restrict__ b,
    float* __restrict__ out, int first)
{
    int i = blockIdx.x * 256 + threadIdx.x;
    if (i >= NN * DO) return;
    float v = agg[i] + b[i & (DO - 1)];
    agg[i] = 0.f;
    v = fmaxf(v, 0.f);
    out[i] = first ? v : (out[i] + v);
}

__global__ __launch_bounds__(256) void norm_kernel(float* __restrict__ out)
{
    int n = (blockIdx.x * 256 + threadIdx.x) >> 6;
    int lane = threadIdx.x & 63;
    if (n >= NN) return;
    size_t idx = (size_t)n * DO + lane;
    float t = out[idx];
    float s = t * t;
    #pragma unroll
    for (int off = 32; off >= 1; off >>= 1) s += __shfl_xor(s, off);
    out[idx] = t / fmaxf(sqrtf(s), 1e-12f);
}

extern "C" void kernel_launch(void* const* d_in, const int* in_sizes, int n_in,
                              void* d_out, int out_size, void* d_ws, size_t ws_size,
                              hipStream_t stream)
{
    const float* x    = (const float*)d_in[0];
    const float* W    = (const float*)d_in[1];
    const float* b    = (const float*)d_in[2];
    const float* vals = (const float*)d_in[3];
    const int*   rows = (const int*)d_in[4];
    const int*   cols = (const int*)d_in[5];
    float* out = (float*)d_out;
    char* ws = (char*)d_ws;

    // ws: xwb 25.6MB | csr 25.6MB | gtot | gstart | gcur | wt
    const size_t O_XW = 0;
    const size_t O_CS = O_XW + (size_t)NR * NN * DO * 2;
    const size_t O_GT = O_CS + (size_t)NR * NE * 8;
    const size_t O_GS = O_GT + (size_t)NBUCK * 4;
    const size_t O_GC = O_GS + (size_t)(NBUCK + 1) * 4;
    const size_t O_WT = O_GC + (size_t)NBUCK * 4;     // bf16 W^T, 64KB
    const size_t NEED = O_WT + 65536;

    if (ws_size >= NEED) {
        __hip_bfloat16* xwb = (__hip_bfloat16*)(ws + O_XW);
        int2* csr   = (int2*)(ws + O_CS);
        int* gtot   = (int*)(ws + O_GT);
        int* gstart = (int*)(ws + O_GS);
        int* gcur   = (int*)(ws + O_GC);
        uint16_t* wt = (uint16_t*)(ws + O_WT);

        hipMemsetAsync(gtot, 0, (size_t)NBUCK * 4, stream);
        prep_kernel<<<dim3(256), dim3(256), 0, stream>>>(W, rows, wt, gtot);
        bases_kernel<<<dim3(1), dim3(512), 0, stream>>>(gtot, gstart, gcur);
        gemm_place_kernel<<<dim3(GEMMB + PWG * NR), dim3(512), 0, stream>>>(
            x, (const uint4*)wt, (uint16_t*)xwb,
            rows, cols, vals, gcur, csr);
        spmm2_kernel<<<dim3(NB), dim3(512), 0, stream>>>(
            (const uint2*)xwb, csr, gstart, b, out);
    } else {
        // sequential atomic-scatter fallback (19.2MB)
        __hip_bfloat16* xwb = (__hip_bfloat16*)ws;
        float* agg = (float*)(ws + (size_t)NN * DO * 2);
        hipMemsetAsync(agg, 0, (size_t)NN * DO * 4, stream);
        for (int r = 0; r < NR; ++r) {
            gemm_kernel<<<dim3((NN + 31) / 32), dim3(256), 0, stream>>>(
                x, W + (size_t)r * DI * DO, xwb);
            scatter_kernel<<<dim3(2048), dim3(256), 0, stream>>>(
                xwb, vals + (size_t)r * NE, rows + (size_t)r * NE,
                cols + (size_t)r * NE, agg);
            accum_kernel<<<dim3((NN * DO + 255) / 256), dim3(256), 0, stream>>>(
                agg, b + (size_t)r * DO, out, r == 0);
        }
        norm_kernel<<<dim3((NN * DO + 255) / 256), dim3(256), 0, stream>>>(out);
    }
}